// Round 3
// baseline (803.306 us; speedup 1.0000x reference)
//
#include <hip/hip_runtime.h>
#include <hip/hip_bf16.h>

#define EPS 1e-8f
#define LAMBDA 1e-3f
#define LN2PI_HALF 0.9189385332046727f

__device__ __forceinline__ float sigmoidf(float x) { return 1.f / (1.f + __expf(-x)); }

// ---------------------------------------------------------------------------
// 1) fused conv stem + primary caps. One 128-thread block per output position.
//    conv: x(32,64,64,1)*W(5,5,1,64) s2 VALID +b, ReLU  -> ys[64] (LDS only)
//    pose = ys@Wp + bp (->128), a = sigmoid(ys@Wa + ba) (->8)
// ---------------------------------------------------------------------------
__global__ __launch_bounds__(128) void stem_primary_kernel(
    const float* __restrict__ x, const float* __restrict__ w,
    const float* __restrict__ bias,
    const float* __restrict__ wp, const float* __restrict__ bp,
    const float* __restrict__ wa, const float* __restrict__ ba,
    float* __restrict__ pose, float* __restrict__ a) {
  int idx = blockIdx.x;                 // b*900 + oi*30 + oj
  int oj = idx % 30;
  int oi = (idx / 30) % 30;
  int b  = idx / 900;
  int t  = threadIdx.x;
  __shared__ float xs[25];
  __shared__ float ys[64];
  if (t < 25) {
    int ki = t / 5, kj = t % 5;
    xs[t] = x[(b * 64 + 2 * oi + ki) * 64 + (2 * oj + kj)];
  }
  __syncthreads();
  if (t < 64) {
    float s = bias[t];
#pragma unroll
    for (int k = 0; k < 25; ++k) s += xs[k] * w[k * 64 + t];
    ys[t] = fmaxf(s, 0.f);
  }
  __syncthreads();
  float s = bp[t];
#pragma unroll 8
  for (int c = 0; c < 64; ++c) s += ys[c] * wp[c * 128 + t];
  pose[(size_t)idx * 128 + t] = s;
  if (t < 8) {
    float q = ba[t];
#pragma unroll 8
    for (int c = 0; c < 64; ++c) q += ys[c] * wa[c * 8 + t];
    a[(size_t)idx * 8 + t] = sigmoidf(q);
  }
}

// ---------------------------------------------------------------------------
// 2) depthwise caps (Cout=1 => EM degenerates to a single M-step; r == 1).
//    One thread per (output capsule, pose component p); 16 threads/problem,
//    16-aligned within the wave. Padded patch positions have a_in = 0 in the
//    reference (zero-pad), so skipping them is exact.
// ---------------------------------------------------------------------------
template <int K, int BC>
__global__ __launch_bounds__(256) void dw_caps_kernel(
    const float* __restrict__ pose_in, const float* __restrict__ a_in,
    const float* __restrict__ Wt,
    const float* __restrict__ bu_p, const float* __restrict__ ba_p,
    float* __restrict__ pose_out, float* __restrict__ a_out,
    int Hin, int Win, int Hout, int Wout) {
  const int pad = K / 2;
  int tid = blockIdx.x * 256 + threadIdx.x;
  int p = tid & 15;
  int prob = tid >> 4;
  int c = prob % BC;
  int t1 = prob / BC;
  int oj = t1 % Wout; t1 /= Wout;
  int oi = t1 % Hout;
  int b = t1 / Hout;
  int ip = p >> 2, l = p & 3;

  // pass A: r_sum and weighted vote sum for component p
  float rsum = 0.f, acc = 0.f;
  for (int k = 0; k < K * K; ++k) {
    int ih = 2 * oi + k / K - pad;
    int iw = 2 * oj + k % K - pad;
    if (ih < 0 || ih >= Hin || iw < 0 || iw >= Win) continue;
    int base = (b * Hin + ih) * Win + iw;
    float ak = a_in[(size_t)base * BC + c];
    rsum += ak;
    const float* pm = pose_in + ((size_t)base * BC + c) * 16 + ip * 4;
    const float* wr = Wt + (k * BC + c) * 16 + l;
    float v = pm[0] * wr[0] + pm[1] * wr[4] + pm[2] * wr[8] + pm[3] * wr[12];
    acc += ak * v;
  }
  float inv = 1.f / (rsum + EPS);
  float mu = acc * inv;

  // pass B: sigma
  float sacc = 0.f;
  for (int k = 0; k < K * K; ++k) {
    int ih = 2 * oi + k / K - pad;
    int iw = 2 * oj + k % K - pad;
    if (ih < 0 || ih >= Hin || iw < 0 || iw >= Win) continue;
    int base = (b * Hin + ih) * Win + iw;
    float ak = a_in[(size_t)base * BC + c];
    const float* pm = pose_in + ((size_t)base * BC + c) * 16 + ip * 4;
    const float* wr = Wt + (k * BC + c) * 16 + l;
    float v = pm[0] * wr[0] + pm[1] * wr[4] + pm[2] * wr[8] + pm[3] * wr[12];
    float dd = v - mu;
    sacc += ak * dd * dd;
  }
  float sg = sacc * inv + EPS;
  float hl = 0.5f * __logf(sg);
  // sum of 0.5*log(sigma) over the 16 pose components of this problem
  float ls = hl;
  ls += __shfl_xor(ls, 1, 64);
  ls += __shfl_xor(ls, 2, 64);
  ls += __shfl_xor(ls, 4, 64);
  ls += __shfl_xor(ls, 8, 64);

  size_t obase = ((size_t)(b * Hout + oi) * Wout + oj) * BC + c;
  pose_out[obase * 16 + p] = mu;
  if (p == 0) {
    float cost = rsum * (16.f * bu_p[0] + ls);
    a_out[obase] = sigmoidf(LAMBDA * (ba_p[0] - cost));
  }
}

// ---------------------------------------------------------------------------
// 3) 1x1 conv caps with full 3-iter EM. COUT=16. One 256-thread block per
//    routing problem; votes/state in LDS. thread t -> (c = t/16, p = t%16).
// ---------------------------------------------------------------------------
template <int BIN>
__global__ __launch_bounds__(256) void cc_em_kernel(
    const float* __restrict__ pose_in, const float* __restrict__ a_arr,
    const float* __restrict__ Wt,
    const float* __restrict__ bu_p, const float* __restrict__ ba_p,
    float* __restrict__ pose_out, float* __restrict__ a_out) {
  constexpr int COUT = 16;
  __shared__ float pm_s[BIN * 16];
  __shared__ float ain_s[BIN];
  __shared__ float v_s[BIN][COUT * 16];
  __shared__ float rw_s[BIN][COUT];       // r * a_in
  __shared__ float mu_s[COUT * 16];
  __shared__ float sg_s[COUT * 16];
  __shared__ float hl_s[COUT * 16];       // 0.5*log(sigma)
  __shared__ float rsum_s[COUT];
  __shared__ float aout_s[COUT];
  __shared__ float lnap_s[BIN][COUT];

  int n = blockIdx.x, t = threadIdx.x;
  int c = t >> 4, p = t & 15;
  if (t < BIN * 16) pm_s[t] = pose_in[(size_t)n * BIN * 16 + t];
  if (t < BIN) ain_s[t] = a_arr[(size_t)n * BIN + t];
  __syncthreads();

  // votes: v[b][c][p] = sum_j pm[b][ip*4+j] * W[b][c][j*4+l]
  int ip = p >> 2, l = p & 3;
#pragma unroll
  for (int b = 0; b < BIN; ++b) {
    const float* wr = Wt + (b * COUT + c) * 16 + l;
    const float* pm = &pm_s[b * 16 + ip * 4];
    v_s[b][t] = pm[0] * wr[0] + pm[1] * wr[4] + pm[2] * wr[8] + pm[3] * wr[12];
  }
  if (t < BIN * COUT) rw_s[t / COUT][t % COUT] = (1.f / COUT) * ain_s[t / COUT];
  __syncthreads();

  for (int it = 0; it < 3; ++it) {
    if (t < COUT) {
      float s = 0.f;
#pragma unroll
      for (int b = 0; b < BIN; ++b) s += rw_s[b][t];
      rsum_s[t] = s;
    }
    __syncthreads();
    {   // mu / sigma for this thread's own (c,p)
      float s = 0.f;
#pragma unroll
      for (int b = 0; b < BIN; ++b) s += rw_s[b][c] * v_s[b][t];
      float mu = s / (rsum_s[c] + EPS);
      mu_s[t] = mu;
      float s2 = 0.f;
#pragma unroll
      for (int b = 0; b < BIN; ++b) { float d = v_s[b][t] - mu; s2 += rw_s[b][c] * d * d; }
      float sg = s2 / (rsum_s[c] + EPS) + EPS;
      sg_s[t] = sg;
      hl_s[t] = 0.5f * __logf(sg);
    }
    __syncthreads();
    if (t < COUT) {
      float lsum = 0.f;
#pragma unroll
      for (int pp = 0; pp < 16; ++pp) lsum += hl_s[t * 16 + pp];
      float cost = rsum_s[t] * (16.f * bu_p[t] + lsum);
      aout_s[t] = sigmoidf(LAMBDA * (ba_p[t] - cost));
    }
    __syncthreads();
    if (it < 2) {
      if (t < BIN * COUT) {
        int b = t / COUT, cc = t % COUT;
        float s = __logf(EPS + aout_s[cc]) - 16.f * LN2PI_HALF;
#pragma unroll
        for (int pp = 0; pp < 16; ++pp) {
          float d = v_s[b][cc * 16 + pp] - mu_s[cc * 16 + pp];
          s += -d * d / (2.f * sg_s[cc * 16 + pp]) - hl_s[cc * 16 + pp];
        }
        lnap_s[b][cc] = s;
      }
      __syncthreads();
      if (t < BIN * COUT) {
        int b = t / COUT, cc = t % COUT;
        float m = -1e30f;
#pragma unroll
        for (int q = 0; q < COUT; ++q) m = fmaxf(m, lnap_s[b][q]);
        float Z = 0.f;
#pragma unroll
        for (int q = 0; q < COUT; ++q) Z += __expf(lnap_s[b][q] - m);
        rw_s[b][cc] = (__expf(lnap_s[b][cc] - m) / Z) * ain_s[b];
      }
      __syncthreads();
    }
  }
  pose_out[(size_t)n * COUT * 16 + t] = mu_s[t];
  if (t < COUT) a_out[(size_t)n * COUT + t] = aout_s[t];
}

// ---------------------------------------------------------------------------
// 4) class caps EM, votes computed ON THE FLY (no votes buffer).
//    Bin=1024 (= (i*8+j)*16+d), Cout=10, 3 iters. One 1024-thread block per
//    image; pose5 image (64KB) stays in L1/L2; cls_w staged in LDS.
//    coordinate addition on vote components 0 (i/8) and 1 (j/8).
// ---------------------------------------------------------------------------
__device__ __forceinline__ float cls_vote(const float* __restrict__ pg,
                                          const float* __restrict__ w_s,
                                          int bi, int c, int ip, int l, int p) {
  int pos = bi >> 4, d = bi & 15;
  const float* pm = pg + pos * 256 + d * 16 + ip * 4;
  const float* wr = w_s + (d * 10 + c) * 16 + l;
  float v = pm[0] * wr[0] + pm[1] * wr[4] + pm[2] * wr[8] + pm[3] * wr[12];
  if (p == 0) v += (float)(pos >> 3) * 0.125f;
  else if (p == 1) v += (float)(pos & 7) * 0.125f;
  return v;
}

__global__ __launch_bounds__(1024) void cls_em_kernel(
    const float* __restrict__ pose5, const float* __restrict__ a5,
    const float* __restrict__ W,
    const float* __restrict__ bu_p, const float* __restrict__ ba_p,
    float* __restrict__ out) {
  __shared__ float rw_s[10][1024];   // 40 KB, r * a_in
  __shared__ float w_s[2560];        // 10 KB, cls_w: [d][e][j*4+l]
  __shared__ float mu_s[160];
  __shared__ float inv_s[160];       // 0.5 / sigma
  __shared__ float hl_s[160];        // 0.5 * log(sigma)
  __shared__ float rsum_s[10];
  __shared__ float aout_s[10];
  __shared__ float part_s[640];

  int b = blockIdx.x, t = threadIdx.x;
  const float* pg = pose5 + (size_t)b * 16384;
  for (int q = t; q < 2560; q += 1024) w_s[q] = W[q];
  float ai = a5[(size_t)b * 1024 + t];
#pragma unroll
  for (int c = 0; c < 10; ++c) rw_s[c][t] = 0.1f * ai;
  __syncthreads();

  for (int it = 0; it < 3; ++it) {
    // r_sum
    if (t < 160) {
      int c = t >> 4, seg = t & 15;
      float s = 0.f;
      for (int q = 0; q < 64; ++q) s += rw_s[c][seg * 64 + q];
      part_s[t] = s;
    }
    __syncthreads();
    if (t < 10) {
      float s = 0.f;
      for (int q = 0; q < 16; ++q) s += part_s[t * 16 + q];
      rsum_s[t] = s;
    }
    __syncthreads();
    // mu partials: thread (c,p,q) sums 256 b_in's, recomputing votes
    if (t < 640) {
      int c = t / 64, p = (t >> 2) & 15, q = t & 3;
      int ip = p >> 2, l = p & 3;
      float s = 0.f;
      for (int x = 0; x < 256; ++x) {
        int bi = (q << 8) + x;
        s += rw_s[c][bi] * cls_vote(pg, w_s, bi, c, ip, l, p);
      }
      part_s[t] = s;
    }
    __syncthreads();
    if (t < 160) {
      int c = t >> 4;
      float s = part_s[4 * t] + part_s[4 * t + 1] + part_s[4 * t + 2] + part_s[4 * t + 3];
      mu_s[t] = s / (rsum_s[c] + EPS);
    }
    __syncthreads();
    // sigma partials
    if (t < 640) {
      int c = t / 64, p = (t >> 2) & 15, q = t & 3;
      int ip = p >> 2, l = p & 3;
      float m = mu_s[c * 16 + p];
      float s = 0.f;
      for (int x = 0; x < 256; ++x) {
        int bi = (q << 8) + x;
        float d = cls_vote(pg, w_s, bi, c, ip, l, p) - m;
        s += rw_s[c][bi] * d * d;
      }
      part_s[t] = s;
    }
    __syncthreads();
    if (t < 160) {
      int c = t >> 4;
      float s = part_s[4 * t] + part_s[4 * t + 1] + part_s[4 * t + 2] + part_s[4 * t + 3];
      float sg = s / (rsum_s[c] + EPS) + EPS;
      inv_s[t] = 0.5f / sg;
      hl_s[t] = 0.5f * __logf(sg);
    }
    __syncthreads();
    if (t < 10) {
      float lsum = 0.f;
      for (int p = 0; p < 16; ++p) lsum += hl_s[t * 16 + p];
      float cost = rsum_s[t] * (16.f * bu_p[t] + lsum);
      aout_s[t] = sigmoidf(LAMBDA * (ba_p[t] - cost));
    }
    __syncthreads();
    if (it < 2) {
      // E-step: thread t = its own b_in; pose row in registers
      float pmr[16];
      const float* pp = pg + (t >> 4) * 256 + (t & 15) * 16;
#pragma unroll
      for (int q = 0; q < 16; ++q) pmr[q] = pp[q];
      float ci = (float)(t >> 7) * 0.125f;
      float cj = (float)((t >> 4) & 7) * 0.125f;
      int d = t & 15;
      float lnap[10];
#pragma unroll
      for (int c = 0; c < 10; ++c) {
        float s = __logf(EPS + aout_s[c]) - 16.f * LN2PI_HALF;
#pragma unroll
        for (int p = 0; p < 16; ++p) {
          int ip = p >> 2, l = p & 3;
          const float* wr = w_s + (d * 10 + c) * 16 + l;
          float v = pmr[ip * 4 + 0] * wr[0] + pmr[ip * 4 + 1] * wr[4]
                  + pmr[ip * 4 + 2] * wr[8] + pmr[ip * 4 + 3] * wr[12];
          if (p == 0) v += ci;
          else if (p == 1) v += cj;
          float dd = v - mu_s[c * 16 + p];
          s += -dd * dd * inv_s[c * 16 + p] - hl_s[c * 16 + p];
        }
        lnap[c] = s;
      }
      float m = -1e30f;
#pragma unroll
      for (int c = 0; c < 10; ++c) m = fmaxf(m, lnap[c]);
      float Z = 0.f;
#pragma unroll
      for (int c = 0; c < 10; ++c) Z += __expf(lnap[c] - m);
      float invZ = ai / Z;
#pragma unroll
      for (int c = 0; c < 10; ++c) rw_s[c][t] = __expf(lnap[c] - m) * invZ;
      __syncthreads();
    }
  }
  if (t < 10) out[b * 10 + t] = aout_s[t];
}

// ---------------------------------------------------------------------------
extern "C" void kernel_launch(void* const* d_in, const int* in_sizes, int n_in,
                              void* d_out, int out_size, void* d_ws, size_t ws_size,
                              hipStream_t stream) {
  const float* x       = (const float*)d_in[0];
  const float* conv1_w = (const float*)d_in[1];
  const float* conv1_b = (const float*)d_in[2];
  const float* pp_w    = (const float*)d_in[3];
  const float* pp_b    = (const float*)d_in[4];
  const float* pa_w    = (const float*)d_in[5];
  const float* pa_b    = (const float*)d_in[6];
  const float* dw1_w   = (const float*)d_in[7];
  const float* dw1_bu  = (const float*)d_in[8];
  const float* dw1_ba  = (const float*)d_in[9];
  const float* cc1_w   = (const float*)d_in[10];
  const float* cc1_bu  = (const float*)d_in[11];
  const float* cc1_ba  = (const float*)d_in[12];
  const float* dw2_w   = (const float*)d_in[13];
  const float* dw2_bu  = (const float*)d_in[14];
  const float* dw2_ba  = (const float*)d_in[15];
  const float* cc2_w   = (const float*)d_in[16];
  const float* cc2_bu  = (const float*)d_in[17];
  const float* cc2_ba  = (const float*)d_in[18];
  const float* cls_w   = (const float*)d_in[19];
  const float* cls_bu  = (const float*)d_in[20];
  const float* cls_ba  = (const float*)d_in[21];
  float* out = (float*)d_out;

  // Workspace layout (floats) with aliasing; total = 4,896,000 f32 = 18.7 MB.
  // pose1/a1 dead after dw1 -> pose3..a5 alias into [0, 3686400).
  float* ws = (float*)d_ws;
  float* pose1 = ws;                  // [0, 3686400)          32*30*30*128
  float* a1    = ws + 3686400;        // [3686400, 3916800)    32*30*30*8
  float* pose2 = ws + 3916800;        // [3916800, 4838400)    32*15*15*128
  float* a2    = ws + 4838400;        // [4838400, 4896000)    32*15*15*8
  float* pose3 = ws;                  // [0, 1843200)          32*15*15*256
  float* a3    = ws + 1843200;        // [1843200, 1958400)    32*15*15*16
  float* pose4 = ws + 1958400;        // [1958400, 2482688)    32*8*8*256
  float* a4    = ws + 2482688;        // [2482688, 2515456)    32*8*8*16
  float* pose5 = ws + 2515456;        // [2515456, 3039744)    32*8*8*256
  float* a5    = ws + 3039744;        // [3039744, 3072512)    32*8*8*16

  // 1. conv stem + primary caps (fused)
  stem_primary_kernel<<<28800, 128, 0, stream>>>(x, conv1_w, conv1_b,
                                                 pp_w, pp_b, pa_w, pa_b, pose1, a1);
  // 2. dw1: K=7 s=2, 30x30 -> 15x15, 8 types. problems = 32*15*15*8 = 57600.
  dw_caps_kernel<7, 8><<<57600 * 16 / 256, 256, 0, stream>>>(
      pose1, a1, dw1_w, dw1_bu, dw1_ba, pose2, a2, 30, 30, 15, 15);
  // 3. cc1: Bin=8 -> Cout=16, n = 32*15*15 = 7200
  cc_em_kernel<8><<<7200, 256, 0, stream>>>(pose2, a2, cc1_w, cc1_bu, cc1_ba, pose3, a3);
  // 4. dw2: K=5 s=2, 15x15 -> 8x8, 16 types. problems = 32*8*8*16 = 32768.
  dw_caps_kernel<5, 16><<<32768 * 16 / 256, 256, 0, stream>>>(
      pose3, a3, dw2_w, dw2_bu, dw2_ba, pose4, a4, 15, 15, 8, 8);
  // 5. cc2: Bin=16 -> Cout=16, n = 32*8*8 = 2048
  cc_em_kernel<16><<<2048, 256, 0, stream>>>(pose4, a4, cc2_w, cc2_bu, cc2_ba, pose5, a5);
  // 6. class caps EM (votes on the fly) -> output activations
  cls_em_kernel<<<32, 1024, 0, stream>>>(pose5, a5, cls_w, cls_bu, cls_ba, out);
}

// Round 4
// 413.829 us; speedup vs baseline: 1.9412x; 1.9412x over previous
//
#include <hip/hip_runtime.h>
#include <hip/hip_bf16.h>

#define EPS 1e-8f
#define LAMBDA 1e-3f
#define LN2PI_HALF 0.9189385332046727f

__device__ __forceinline__ float sigmoidf(float x) { return 1.f / (1.f + __expf(-x)); }

// ---------------------------------------------------------------------------
// 1) fused conv stem + primary caps. One 128-thread block per output position.
// ---------------------------------------------------------------------------
__global__ __launch_bounds__(128) void stem_primary_kernel(
    const float* __restrict__ x, const float* __restrict__ w,
    const float* __restrict__ bias,
    const float* __restrict__ wp, const float* __restrict__ bp,
    const float* __restrict__ wa, const float* __restrict__ ba,
    float* __restrict__ pose, float* __restrict__ a) {
  int idx = blockIdx.x;                 // b*900 + oi*30 + oj
  int oj = idx % 30;
  int oi = (idx / 30) % 30;
  int b  = idx / 900;
  int t  = threadIdx.x;
  __shared__ float xs[25];
  __shared__ float ys[64];
  if (t < 25) {
    int ki = t / 5, kj = t % 5;
    xs[t] = x[(b * 64 + 2 * oi + ki) * 64 + (2 * oj + kj)];
  }
  __syncthreads();
  if (t < 64) {
    float s = bias[t];
#pragma unroll
    for (int k = 0; k < 25; ++k) s += xs[k] * w[k * 64 + t];
    ys[t] = fmaxf(s, 0.f);
  }
  __syncthreads();
  float s = bp[t];
#pragma unroll 8
  for (int c = 0; c < 64; ++c) s += ys[c] * wp[c * 128 + t];
  pose[(size_t)idx * 128 + t] = s;
  if (t < 8) {
    float q = ba[t];
#pragma unroll 8
    for (int c = 0; c < 64; ++c) q += ys[c] * wa[c * 8 + t];
    a[(size_t)idx * 8 + t] = sigmoidf(q);
  }
}

// ---------------------------------------------------------------------------
// 2) depthwise caps (Cout=1 => EM degenerates to a single M-step; r == 1).
// ---------------------------------------------------------------------------
template <int K, int BC>
__global__ __launch_bounds__(256) void dw_caps_kernel(
    const float* __restrict__ pose_in, const float* __restrict__ a_in,
    const float* __restrict__ Wt,
    const float* __restrict__ bu_p, const float* __restrict__ ba_p,
    float* __restrict__ pose_out, float* __restrict__ a_out,
    int Hin, int Win, int Hout, int Wout) {
  const int pad = K / 2;
  int tid = blockIdx.x * 256 + threadIdx.x;
  int p = tid & 15;
  int prob = tid >> 4;
  int c = prob % BC;
  int t1 = prob / BC;
  int oj = t1 % Wout; t1 /= Wout;
  int oi = t1 % Hout;
  int b = t1 / Hout;
  int ip = p >> 2, l = p & 3;

  float rsum = 0.f, acc = 0.f;
  for (int k = 0; k < K * K; ++k) {
    int ih = 2 * oi + k / K - pad;
    int iw = 2 * oj + k % K - pad;
    if (ih < 0 || ih >= Hin || iw < 0 || iw >= Win) continue;
    int base = (b * Hin + ih) * Win + iw;
    float ak = a_in[(size_t)base * BC + c];
    rsum += ak;
    const float* pm = pose_in + ((size_t)base * BC + c) * 16 + ip * 4;
    const float* wr = Wt + (k * BC + c) * 16 + l;
    float v = pm[0] * wr[0] + pm[1] * wr[4] + pm[2] * wr[8] + pm[3] * wr[12];
    acc += ak * v;
  }
  float inv = 1.f / (rsum + EPS);
  float mu = acc * inv;

  float sacc = 0.f;
  for (int k = 0; k < K * K; ++k) {
    int ih = 2 * oi + k / K - pad;
    int iw = 2 * oj + k % K - pad;
    if (ih < 0 || ih >= Hin || iw < 0 || iw >= Win) continue;
    int base = (b * Hin + ih) * Win + iw;
    float ak = a_in[(size_t)base * BC + c];
    const float* pm = pose_in + ((size_t)base * BC + c) * 16 + ip * 4;
    const float* wr = Wt + (k * BC + c) * 16 + l;
    float v = pm[0] * wr[0] + pm[1] * wr[4] + pm[2] * wr[8] + pm[3] * wr[12];
    float dd = v - mu;
    sacc += ak * dd * dd;
  }
  float sg = sacc * inv + EPS;
  float hl = 0.5f * __logf(sg);
  float ls = hl;
  ls += __shfl_xor(ls, 1, 64);
  ls += __shfl_xor(ls, 2, 64);
  ls += __shfl_xor(ls, 4, 64);
  ls += __shfl_xor(ls, 8, 64);

  size_t obase = ((size_t)(b * Hout + oi) * Wout + oj) * BC + c;
  pose_out[obase * 16 + p] = mu;
  if (p == 0) {
    float cost = rsum * (16.f * bu_p[0] + ls);
    a_out[obase] = sigmoidf(LAMBDA * (ba_p[0] - cost));
  }
}

// ---------------------------------------------------------------------------
// 3) 1x1 conv caps with full 3-iter EM. COUT=16. One 256-thread block per
//    routing problem; votes/state in LDS. thread t -> (c = t/16, p = t%16).
// ---------------------------------------------------------------------------
template <int BIN>
__global__ __launch_bounds__(256) void cc_em_kernel(
    const float* __restrict__ pose_in, const float* __restrict__ a_arr,
    const float* __restrict__ Wt,
    const float* __restrict__ bu_p, const float* __restrict__ ba_p,
    float* __restrict__ pose_out, float* __restrict__ a_out) {
  constexpr int COUT = 16;
  __shared__ float pm_s[BIN * 16];
  __shared__ float ain_s[BIN];
  __shared__ float v_s[BIN][COUT * 16];
  __shared__ float rw_s[BIN][COUT];
  __shared__ float mu_s[COUT * 16];
  __shared__ float sg_s[COUT * 16];
  __shared__ float hl_s[COUT * 16];
  __shared__ float rsum_s[COUT];
  __shared__ float aout_s[COUT];
  __shared__ float lnap_s[BIN][COUT];

  int n = blockIdx.x, t = threadIdx.x;
  int c = t >> 4, p = t & 15;
  if (t < BIN * 16) pm_s[t] = pose_in[(size_t)n * BIN * 16 + t];
  if (t < BIN) ain_s[t] = a_arr[(size_t)n * BIN + t];
  __syncthreads();

  int ip = p >> 2, l = p & 3;
#pragma unroll
  for (int b = 0; b < BIN; ++b) {
    const float* wr = Wt + (b * COUT + c) * 16 + l;
    const float* pm = &pm_s[b * 16 + ip * 4];
    v_s[b][t] = pm[0] * wr[0] + pm[1] * wr[4] + pm[2] * wr[8] + pm[3] * wr[12];
  }
  if (t < BIN * COUT) rw_s[t / COUT][t % COUT] = (1.f / COUT) * ain_s[t / COUT];
  __syncthreads();

  for (int it = 0; it < 3; ++it) {
    if (t < COUT) {
      float s = 0.f;
#pragma unroll
      for (int b = 0; b < BIN; ++b) s += rw_s[b][t];
      rsum_s[t] = s;
    }
    __syncthreads();
    {
      float s = 0.f;
#pragma unroll
      for (int b = 0; b < BIN; ++b) s += rw_s[b][c] * v_s[b][t];
      float mu = s / (rsum_s[c] + EPS);
      mu_s[t] = mu;
      float s2 = 0.f;
#pragma unroll
      for (int b = 0; b < BIN; ++b) { float d = v_s[b][t] - mu; s2 += rw_s[b][c] * d * d; }
      float sg = s2 / (rsum_s[c] + EPS) + EPS;
      sg_s[t] = sg;
      hl_s[t] = 0.5f * __logf(sg);
    }
    __syncthreads();
    if (t < COUT) {
      float lsum = 0.f;
#pragma unroll
      for (int pp = 0; pp < 16; ++pp) lsum += hl_s[t * 16 + pp];
      float cost = rsum_s[t] * (16.f * bu_p[t] + lsum);
      aout_s[t] = sigmoidf(LAMBDA * (ba_p[t] - cost));
    }
    __syncthreads();
    if (it < 2) {
      if (t < BIN * COUT) {
        int b = t / COUT, cc = t % COUT;
        float s = __logf(EPS + aout_s[cc]) - 16.f * LN2PI_HALF;
#pragma unroll
        for (int pp = 0; pp < 16; ++pp) {
          float d = v_s[b][cc * 16 + pp] - mu_s[cc * 16 + pp];
          s += -d * d / (2.f * sg_s[cc * 16 + pp]) - hl_s[cc * 16 + pp];
        }
        lnap_s[b][cc] = s;
      }
      __syncthreads();
      if (t < BIN * COUT) {
        int b = t / COUT, cc = t % COUT;
        float m = -1e30f;
#pragma unroll
        for (int q = 0; q < COUT; ++q) m = fmaxf(m, lnap_s[b][q]);
        float Z = 0.f;
#pragma unroll
        for (int q = 0; q < COUT; ++q) Z += __expf(lnap_s[b][q] - m);
        rw_s[b][cc] = (__expf(lnap_s[b][cc] - m) / Z) * ain_s[b];
      }
      __syncthreads();
    }
  }
  pose_out[(size_t)n * COUT * 16 + t] = mu_s[t];
  if (t < COUT) a_out[(size_t)n * COUT + t] = aout_s[t];
}

// ---------------------------------------------------------------------------
// 4) class caps EM — REWRITTEN. One 640-thread block (10 waves) per image.
//    M-step: wave = output capsule c, lane = b_in chunk element; votes in
//    registers; single-pass Σrw, Σrw·v, Σrw·v² (33 accs) + butterfly reduce.
//    E-step: thread-per-b_in; all LDS reads broadcast or stride-1.
//    w2 transposed to [c][jj][d] so lane-varying d is contiguous (no
//    bank conflicts; old layout had 16-way conflicts, 4.3M cycles/dispatch).
// ---------------------------------------------------------------------------
__global__ __launch_bounds__(640) void cls_em_kernel(
    const float* __restrict__ pose5, const float* __restrict__ a5,
    const float* __restrict__ W,
    const float* __restrict__ bu_p, const float* __restrict__ ba_p,
    float* __restrict__ out) {
  __shared__ float X[10][1024];      // rw = r * a_in        (40 KB)
  __shared__ float w2[10][16][16];   // [c][jj][d]           (10 KB)
  __shared__ float ain_s[1024];      //                      (4 KB)
  __shared__ float mu_s[160];
  __shared__ float inv2_s[160];      // 0.5 / sigma^2
  __shared__ float base_s[10];       // log(eps+aout) - Σhl - 16*LN2PI_HALF
  __shared__ float aout_s[10];

  int b = blockIdx.x, t = threadIdx.x;
  int wave = t >> 6, lane = t & 63;
  const float* pg = pose5 + (size_t)b * 16384;

  for (int q = t; q < 2560; q += 640) {
    int dd = q & 15, jj = (q >> 4) & 15, c = q >> 8;
    w2[c][jj][dd] = W[(dd * 10 + c) * 16 + jj];
  }
  for (int q = t; q < 1024; q += 640) {
    float av = a5[(size_t)b * 1024 + q];
    ain_s[q] = av;
    float r0 = 0.1f * av;
#pragma unroll
    for (int c = 0; c < 10; ++c) X[c][q] = r0;
  }
  __syncthreads();

  for (int it = 0; it < 3; ++it) {
    // ---------------- M step: wave handles c = wave ----------------
    {
      const int c = wave;
      const int d = lane & 15;
      float wf[16];
#pragma unroll
      for (int jj = 0; jj < 16; ++jj) wf[jj] = w2[c][jj][d];
      float sA = 0.f;
      float sV[16], sV2[16];
#pragma unroll
      for (int p = 0; p < 16; ++p) { sV[p] = 0.f; sV2[p] = 0.f; }
      for (int ch = 0; ch < 16; ++ch) {
        int bi = ch * 64 + lane;
        int pos = bi >> 4;
        float ci = (float)(pos >> 3) * 0.125f;
        float cj = (float)(pos & 7) * 0.125f;
        const float* pp = pg + pos * 256 + d * 16;
        float pmr[16];
#pragma unroll
        for (int q = 0; q < 16; ++q) pmr[q] = pp[q];
        float rw = X[c][bi];
        sA += rw;
#pragma unroll
        for (int p = 0; p < 16; ++p) {
          int ip = p >> 2, l = p & 3;
          float v = pmr[ip * 4 + 0] * wf[0 * 4 + l] + pmr[ip * 4 + 1] * wf[1 * 4 + l]
                  + pmr[ip * 4 + 2] * wf[2 * 4 + l] + pmr[ip * 4 + 3] * wf[3 * 4 + l];
          if (p == 0) v += ci;
          else if (p == 1) v += cj;
          float rv = rw * v;
          sV[p] += rv;
          sV2[p] += rv * v;
        }
      }
#pragma unroll
      for (int off = 1; off < 64; off <<= 1) {
        sA += __shfl_xor(sA, off, 64);
#pragma unroll
        for (int p = 0; p < 16; ++p) {
          sV[p]  += __shfl_xor(sV[p],  off, 64);
          sV2[p] += __shfl_xor(sV2[p], off, 64);
        }
      }
      if (lane == 0) {
        float inv = 1.f / (sA + EPS);
        float S = sA * inv;
        float lsum = 0.f;
#pragma unroll
        for (int p = 0; p < 16; ++p) {
          float mu = sV[p] * inv;
          float sg = sV2[p] * inv - mu * mu * (2.f - S) + EPS;
          sg = fmaxf(sg, EPS);
          mu_s[c * 16 + p] = mu;
          inv2_s[c * 16 + p] = 0.5f / sg;
          lsum += 0.5f * __logf(sg);
        }
        float cost = sA * (16.f * bu_p[c] + lsum);
        float ao = sigmoidf(LAMBDA * (ba_p[c] - cost));
        aout_s[c] = ao;
        base_s[c] = __logf(EPS + ao) - lsum - 16.f * LN2PI_HALF;
      }
    }
    __syncthreads();
    // ---------------- E step ----------------
    if (it < 2) {
#pragma unroll
      for (int rep = 0; rep < 2; ++rep) {
        int bi = t + rep * 640;
        if (bi < 1024) {
          int pos = bi >> 4, d2 = bi & 15;
          float ci = (float)(pos >> 3) * 0.125f;
          float cj = (float)(pos & 7) * 0.125f;
          const float* pp = pg + pos * 256 + d2 * 16;
          float pmr[16];
#pragma unroll
          for (int q = 0; q < 16; ++q) pmr[q] = pp[q];
          float lnap[10];
#pragma unroll
          for (int c = 0; c < 10; ++c) {
            float wf[16];
#pragma unroll
            for (int jj = 0; jj < 16; ++jj) wf[jj] = w2[c][jj][d2];
            float s = base_s[c];
#pragma unroll
            for (int p = 0; p < 16; ++p) {
              int ip = p >> 2, l = p & 3;
              float v = pmr[ip * 4 + 0] * wf[0 * 4 + l] + pmr[ip * 4 + 1] * wf[1 * 4 + l]
                      + pmr[ip * 4 + 2] * wf[2 * 4 + l] + pmr[ip * 4 + 3] * wf[3 * 4 + l];
              if (p == 0) v += ci;
              else if (p == 1) v += cj;
              float dd = v - mu_s[c * 16 + p];
              s -= dd * dd * inv2_s[c * 16 + p];
            }
            lnap[c] = s;
          }
          float m = -1e30f;
#pragma unroll
          for (int c = 0; c < 10; ++c) m = fmaxf(m, lnap[c]);
          float Z = 0.f;
          float ex[10];
#pragma unroll
          for (int c = 0; c < 10; ++c) { ex[c] = __expf(lnap[c] - m); Z += ex[c]; }
          float invZ = ain_s[bi] / Z;
#pragma unroll
          for (int c = 0; c < 10; ++c) X[c][bi] = ex[c] * invZ;
        }
      }
      __syncthreads();
    }
  }
  if (t < 10) out[b * 10 + t] = aout_s[t];
}

// ---------------------------------------------------------------------------
extern "C" void kernel_launch(void* const* d_in, const int* in_sizes, int n_in,
                              void* d_out, int out_size, void* d_ws, size_t ws_size,
                              hipStream_t stream) {
  const float* x       = (const float*)d_in[0];
  const float* conv1_w = (const float*)d_in[1];
  const float* conv1_b = (const float*)d_in[2];
  const float* pp_w    = (const float*)d_in[3];
  const float* pp_b    = (const float*)d_in[4];
  const float* pa_w    = (const float*)d_in[5];
  const float* pa_b    = (const float*)d_in[6];
  const float* dw1_w   = (const float*)d_in[7];
  const float* dw1_bu  = (const float*)d_in[8];
  const float* dw1_ba  = (const float*)d_in[9];
  const float* cc1_w   = (const float*)d_in[10];
  const float* cc1_bu  = (const float*)d_in[11];
  const float* cc1_ba  = (const float*)d_in[12];
  const float* dw2_w   = (const float*)d_in[13];
  const float* dw2_bu  = (const float*)d_in[14];
  const float* dw2_ba  = (const float*)d_in[15];
  const float* cc2_w   = (const float*)d_in[16];
  const float* cc2_bu  = (const float*)d_in[17];
  const float* cc2_ba  = (const float*)d_in[18];
  const float* cls_w   = (const float*)d_in[19];
  const float* cls_bu  = (const float*)d_in[20];
  const float* cls_ba  = (const float*)d_in[21];
  float* out = (float*)d_out;

  float* ws = (float*)d_ws;
  float* pose1 = ws;                  // [0, 3686400)          32*30*30*128
  float* a1    = ws + 3686400;        // [3686400, 3916800)    32*30*30*8
  float* pose2 = ws + 3916800;        // [3916800, 4838400)    32*15*15*128
  float* a2    = ws + 4838400;        // [4838400, 4896000)    32*15*15*8
  float* pose3 = ws;                  // [0, 1843200)          32*15*15*256
  float* a3    = ws + 1843200;        // 32*15*15*16
  float* pose4 = ws + 1958400;        // 32*8*8*256
  float* a4    = ws + 2482688;        // 32*8*8*16
  float* pose5 = ws + 2515456;        // 32*8*8*256
  float* a5    = ws + 3039744;        // 32*8*8*16

  stem_primary_kernel<<<28800, 128, 0, stream>>>(x, conv1_w, conv1_b,
                                                 pp_w, pp_b, pa_w, pa_b, pose1, a1);
  dw_caps_kernel<7, 8><<<57600 * 16 / 256, 256, 0, stream>>>(
      pose1, a1, dw1_w, dw1_bu, dw1_ba, pose2, a2, 30, 30, 15, 15);
  cc_em_kernel<8><<<7200, 256, 0, stream>>>(pose2, a2, cc1_w, cc1_bu, cc1_ba, pose3, a3);
  dw_caps_kernel<5, 16><<<32768 * 16 / 256, 256, 0, stream>>>(
      pose3, a3, dw2_w, dw2_bu, dw2_ba, pose4, a4, 15, 15, 8, 8);
  cc_em_kernel<16><<<2048, 256, 0, stream>>>(pose4, a4, cc2_w, cc2_bu, cc2_ba, pose5, a5);
  cls_em_kernel<<<32, 640, 0, stream>>>(pose5, a5, cls_w, cls_bu, cls_ba, out);
}

// Round 5
// 353.786 us; speedup vs baseline: 2.2706x; 1.1697x over previous
//
#include <hip/hip_runtime.h>
#include <hip/hip_bf16.h>

#define EPS 1e-8f
#define LAMBDA 1e-3f
#define LN2PI_HALF 0.9189385332046727f

__device__ __forceinline__ float sigmoidf(float x) { return 1.f / (1.f + __expf(-x)); }

// ---------------------------------------------------------------------------
// 1) fused conv stem + primary caps. One 128-thread block per output position.
// ---------------------------------------------------------------------------
__global__ __launch_bounds__(128) void stem_primary_kernel(
    const float* __restrict__ x, const float* __restrict__ w,
    const float* __restrict__ bias,
    const float* __restrict__ wp, const float* __restrict__ bp,
    const float* __restrict__ wa, const float* __restrict__ ba,
    float* __restrict__ pose, float* __restrict__ a) {
  int idx = blockIdx.x;                 // b*900 + oi*30 + oj
  int oj = idx % 30;
  int oi = (idx / 30) % 30;
  int b  = idx / 900;
  int t  = threadIdx.x;
  __shared__ float xs[25];
  __shared__ float ys[64];
  if (t < 25) {
    int ki = t / 5, kj = t % 5;
    xs[t] = x[(b * 64 + 2 * oi + ki) * 64 + (2 * oj + kj)];
  }
  __syncthreads();
  if (t < 64) {
    float s = bias[t];
#pragma unroll
    for (int k = 0; k < 25; ++k) s += xs[k] * w[k * 64 + t];
    ys[t] = fmaxf(s, 0.f);
  }
  __syncthreads();
  float s = bp[t];
#pragma unroll 8
  for (int c = 0; c < 64; ++c) s += ys[c] * wp[c * 128 + t];
  pose[(size_t)idx * 128 + t] = s;
  if (t < 8) {
    float q = ba[t];
#pragma unroll 8
    for (int c = 0; c < 64; ++c) q += ys[c] * wa[c * 8 + t];
    a[(size_t)idx * 8 + t] = sigmoidf(q);
  }
}

// ---------------------------------------------------------------------------
// 2) depthwise caps (Cout=1 => EM degenerates to a single M-step; r == 1).
//    SINGLE-PASS: Σa, Σa·v, Σa·v² in one tap walk; σ² = E[v²] − μ²(2−S).
//    (Was 2-pass: re-loaded pose+weights and recomputed votes for σ² —
//     FETCH_SIZE 27 MB ≈ 2× input, 107 µs/dispatch.)
//    ki/kj nested loop removes per-tap k/K div+mod and hoists row bounds.
// ---------------------------------------------------------------------------
template <int K, int BC>
__global__ __launch_bounds__(256) void dw_caps_kernel(
    const float* __restrict__ pose_in, const float* __restrict__ a_in,
    const float* __restrict__ Wt,
    const float* __restrict__ bu_p, const float* __restrict__ ba_p,
    float* __restrict__ pose_out, float* __restrict__ a_out,
    int Hin, int Win, int Hout, int Wout) {
  const int pad = K / 2;
  int tid = blockIdx.x * 256 + threadIdx.x;
  int p = tid & 15;
  int prob = tid >> 4;
  int c = prob % BC;
  int t1 = prob / BC;
  int oj = t1 % Wout; t1 /= Wout;
  int oi = t1 % Hout;
  int b = t1 / Hout;
  int ip = p >> 2, l = p & 3;

  int ih0 = 2 * oi - pad, iw0 = 2 * oj - pad;
  float rsum = 0.f, acc = 0.f, acc2 = 0.f;
#pragma unroll
  for (int ki = 0; ki < K; ++ki) {
    int ih = ih0 + ki;
    if (ih < 0 || ih >= Hin) continue;
    int rowbase = (b * Hin + ih) * Win;
#pragma unroll
    for (int kj = 0; kj < K; ++kj) {
      int iw = iw0 + kj;
      if (iw < 0 || iw >= Win) continue;
      int base = rowbase + iw;
      float ak = a_in[(size_t)base * BC + c];
      const float* pm = pose_in + ((size_t)base * BC + c) * 16 + ip * 4;
      const float* wr = Wt + ((ki * K + kj) * BC + c) * 16 + l;
      float v = pm[0] * wr[0] + pm[1] * wr[4] + pm[2] * wr[8] + pm[3] * wr[12];
      rsum += ak;
      float av = ak * v;
      acc += av;
      acc2 += av * v;
    }
  }
  float inv = 1.f / (rsum + EPS);
  float mu = acc * inv;
  float S = rsum * inv;
  float sg = acc2 * inv - mu * mu * (2.f - S);
  sg = fmaxf(sg, 0.f) + EPS;
  float hl = 0.5f * __logf(sg);
  float ls = hl;
  ls += __shfl_xor(ls, 1, 64);
  ls += __shfl_xor(ls, 2, 64);
  ls += __shfl_xor(ls, 4, 64);
  ls += __shfl_xor(ls, 8, 64);

  size_t obase = ((size_t)(b * Hout + oi) * Wout + oj) * BC + c;
  pose_out[obase * 16 + p] = mu;
  if (p == 0) {
    float cost = rsum * (16.f * bu_p[0] + ls);
    a_out[obase] = sigmoidf(LAMBDA * (ba_p[0] - cost));
  }
}

// ---------------------------------------------------------------------------
// 3) 1x1 conv caps with full 3-iter EM. COUT=16. One 256-thread block per
//    routing problem; votes/state in LDS. thread t -> (c = t/16, p = t%16).
// ---------------------------------------------------------------------------
template <int BIN>
__global__ __launch_bounds__(256) void cc_em_kernel(
    const float* __restrict__ pose_in, const float* __restrict__ a_arr,
    const float* __restrict__ Wt,
    const float* __restrict__ bu_p, const float* __restrict__ ba_p,
    float* __restrict__ pose_out, float* __restrict__ a_out) {
  constexpr int COUT = 16;
  __shared__ float pm_s[BIN * 16];
  __shared__ float ain_s[BIN];
  __shared__ float v_s[BIN][COUT * 16];
  __shared__ float rw_s[BIN][COUT];
  __shared__ float mu_s[COUT * 16];
  __shared__ float sg_s[COUT * 16];
  __shared__ float hl_s[COUT * 16];
  __shared__ float rsum_s[COUT];
  __shared__ float aout_s[COUT];
  __shared__ float lnap_s[BIN][COUT];

  int n = blockIdx.x, t = threadIdx.x;
  int c = t >> 4, p = t & 15;
  if (t < BIN * 16) pm_s[t] = pose_in[(size_t)n * BIN * 16 + t];
  if (t < BIN) ain_s[t] = a_arr[(size_t)n * BIN + t];
  __syncthreads();

  int ip = p >> 2, l = p & 3;
#pragma unroll
  for (int b = 0; b < BIN; ++b) {
    const float* wr = Wt + (b * COUT + c) * 16 + l;
    const float* pm = &pm_s[b * 16 + ip * 4];
    v_s[b][t] = pm[0] * wr[0] + pm[1] * wr[4] + pm[2] * wr[8] + pm[3] * wr[12];
  }
  if (t < BIN * COUT) rw_s[t / COUT][t % COUT] = (1.f / COUT) * ain_s[t / COUT];
  __syncthreads();

  for (int it = 0; it < 3; ++it) {
    if (t < COUT) {
      float s = 0.f;
#pragma unroll
      for (int b = 0; b < BIN; ++b) s += rw_s[b][t];
      rsum_s[t] = s;
    }
    __syncthreads();
    {
      float s = 0.f;
#pragma unroll
      for (int b = 0; b < BIN; ++b) s += rw_s[b][c] * v_s[b][t];
      float mu = s / (rsum_s[c] + EPS);
      mu_s[t] = mu;
      float s2 = 0.f;
#pragma unroll
      for (int b = 0; b < BIN; ++b) { float d = v_s[b][t] - mu; s2 += rw_s[b][c] * d * d; }
      float sg = s2 / (rsum_s[c] + EPS) + EPS;
      sg_s[t] = sg;
      hl_s[t] = 0.5f * __logf(sg);
    }
    __syncthreads();
    if (t < COUT) {
      float lsum = 0.f;
#pragma unroll
      for (int pp = 0; pp < 16; ++pp) lsum += hl_s[t * 16 + pp];
      float cost = rsum_s[t] * (16.f * bu_p[t] + lsum);
      aout_s[t] = sigmoidf(LAMBDA * (ba_p[t] - cost));
    }
    __syncthreads();
    if (it < 2) {
      if (t < BIN * COUT) {
        int b = t / COUT, cc = t % COUT;
        float s = __logf(EPS + aout_s[cc]) - 16.f * LN2PI_HALF;
#pragma unroll
        for (int pp = 0; pp < 16; ++pp) {
          float d = v_s[b][cc * 16 + pp] - mu_s[cc * 16 + pp];
          s += -d * d / (2.f * sg_s[cc * 16 + pp]) - hl_s[cc * 16 + pp];
        }
        lnap_s[b][cc] = s;
      }
      __syncthreads();
      if (t < BIN * COUT) {
        int b = t / COUT, cc = t % COUT;
        float m = -1e30f;
#pragma unroll
        for (int q = 0; q < COUT; ++q) m = fmaxf(m, lnap_s[b][q]);
        float Z = 0.f;
#pragma unroll
        for (int q = 0; q < COUT; ++q) Z += __expf(lnap_s[b][q] - m);
        rw_s[b][cc] = (__expf(lnap_s[b][cc] - m) / Z) * ain_s[b];
      }
      __syncthreads();
    }
  }
  pose_out[(size_t)n * COUT * 16 + t] = mu_s[t];
  if (t < COUT) a_out[(size_t)n * COUT + t] = aout_s[t];
}

// ---------------------------------------------------------------------------
// 4) class caps EM. One 640-thread block (10 waves) per image.
//    M-step: wave = output capsule; votes in registers; single-pass moments
//    + butterfly reduce. E-step: thread-per-b_in; conflict-free LDS.
// ---------------------------------------------------------------------------
__global__ __launch_bounds__(640) void cls_em_kernel(
    const float* __restrict__ pose5, const float* __restrict__ a5,
    const float* __restrict__ W,
    const float* __restrict__ bu_p, const float* __restrict__ ba_p,
    float* __restrict__ out) {
  __shared__ float X[10][1024];      // rw = r * a_in        (40 KB)
  __shared__ float w2[10][16][16];   // [c][jj][d]           (10 KB)
  __shared__ float ain_s[1024];      //                      (4 KB)
  __shared__ float mu_s[160];
  __shared__ float inv2_s[160];      // 0.5 / sigma^2
  __shared__ float base_s[10];       // log(eps+aout) - Σhl - 16*LN2PI_HALF
  __shared__ float aout_s[10];

  int b = blockIdx.x, t = threadIdx.x;
  int wave = t >> 6, lane = t & 63;
  const float* pg = pose5 + (size_t)b * 16384;

  for (int q = t; q < 2560; q += 640) {
    int dd = q & 15, jj = (q >> 4) & 15, c = q >> 8;
    w2[c][jj][dd] = W[(dd * 10 + c) * 16 + jj];
  }
  for (int q = t; q < 1024; q += 640) {
    float av = a5[(size_t)b * 1024 + q];
    ain_s[q] = av;
    float r0 = 0.1f * av;
#pragma unroll
    for (int c = 0; c < 10; ++c) X[c][q] = r0;
  }
  __syncthreads();

  for (int it = 0; it < 3; ++it) {
    {
      const int c = wave;
      const int d = lane & 15;
      float wf[16];
#pragma unroll
      for (int jj = 0; jj < 16; ++jj) wf[jj] = w2[c][jj][d];
      float sA = 0.f;
      float sV[16], sV2[16];
#pragma unroll
      for (int p = 0; p < 16; ++p) { sV[p] = 0.f; sV2[p] = 0.f; }
      for (int ch = 0; ch < 16; ++ch) {
        int bi = ch * 64 + lane;
        int pos = bi >> 4;
        float ci = (float)(pos >> 3) * 0.125f;
        float cj = (float)(pos & 7) * 0.125f;
        const float* pp = pg + pos * 256 + d * 16;
        float pmr[16];
#pragma unroll
        for (int q = 0; q < 16; ++q) pmr[q] = pp[q];
        float rw = X[c][bi];
        sA += rw;
#pragma unroll
        for (int p = 0; p < 16; ++p) {
          int ip = p >> 2, l = p & 3;
          float v = pmr[ip * 4 + 0] * wf[0 * 4 + l] + pmr[ip * 4 + 1] * wf[1 * 4 + l]
                  + pmr[ip * 4 + 2] * wf[2 * 4 + l] + pmr[ip * 4 + 3] * wf[3 * 4 + l];
          if (p == 0) v += ci;
          else if (p == 1) v += cj;
          float rv = rw * v;
          sV[p] += rv;
          sV2[p] += rv * v;
        }
      }
#pragma unroll
      for (int off = 1; off < 64; off <<= 1) {
        sA += __shfl_xor(sA, off, 64);
#pragma unroll
        for (int p = 0; p < 16; ++p) {
          sV[p]  += __shfl_xor(sV[p],  off, 64);
          sV2[p] += __shfl_xor(sV2[p], off, 64);
        }
      }
      if (lane == 0) {
        float inv = 1.f / (sA + EPS);
        float S = sA * inv;
        float lsum = 0.f;
#pragma unroll
        for (int p = 0; p < 16; ++p) {
          float mu = sV[p] * inv;
          float sg = sV2[p] * inv - mu * mu * (2.f - S) + EPS;
          sg = fmaxf(sg, EPS);
          mu_s[c * 16 + p] = mu;
          inv2_s[c * 16 + p] = 0.5f / sg;
          lsum += 0.5f * __logf(sg);
        }
        float cost = sA * (16.f * bu_p[c] + lsum);
        float ao = sigmoidf(LAMBDA * (ba_p[c] - cost));
        aout_s[c] = ao;
        base_s[c] = __logf(EPS + ao) - lsum - 16.f * LN2PI_HALF;
      }
    }
    __syncthreads();
    if (it < 2) {
#pragma unroll
      for (int rep = 0; rep < 2; ++rep) {
        int bi = t + rep * 640;
        if (bi < 1024) {
          int pos = bi >> 4, d2 = bi & 15;
          float ci = (float)(pos >> 3) * 0.125f;
          float cj = (float)(pos & 7) * 0.125f;
          const float* pp = pg + pos * 256 + d2 * 16;
          float pmr[16];
#pragma unroll
          for (int q = 0; q < 16; ++q) pmr[q] = pp[q];
          float lnap[10];
#pragma unroll
          for (int c = 0; c < 10; ++c) {
            float wf[16];
#pragma unroll
            for (int jj = 0; jj < 16; ++jj) wf[jj] = w2[c][jj][d2];
            float s = base_s[c];
#pragma unroll
            for (int p = 0; p < 16; ++p) {
              int ip = p >> 2, l = p & 3;
              float v = pmr[ip * 4 + 0] * wf[0 * 4 + l] + pmr[ip * 4 + 1] * wf[1 * 4 + l]
                      + pmr[ip * 4 + 2] * wf[2 * 4 + l] + pmr[ip * 4 + 3] * wf[3 * 4 + l];
              if (p == 0) v += ci;
              else if (p == 1) v += cj;
              float dd = v - mu_s[c * 16 + p];
              s -= dd * dd * inv2_s[c * 16 + p];
            }
            lnap[c] = s;
          }
          float m = -1e30f;
#pragma unroll
          for (int c = 0; c < 10; ++c) m = fmaxf(m, lnap[c]);
          float Z = 0.f;
          float ex[10];
#pragma unroll
          for (int c = 0; c < 10; ++c) { ex[c] = __expf(lnap[c] - m); Z += ex[c]; }
          float invZ = ain_s[bi] / Z;
#pragma unroll
          for (int c = 0; c < 10; ++c) X[c][bi] = ex[c] * invZ;
        }
      }
      __syncthreads();
    }
  }
  if (t < 10) out[b * 10 + t] = aout_s[t];
}

// ---------------------------------------------------------------------------
extern "C" void kernel_launch(void* const* d_in, const int* in_sizes, int n_in,
                              void* d_out, int out_size, void* d_ws, size_t ws_size,
                              hipStream_t stream) {
  const float* x       = (const float*)d_in[0];
  const float* conv1_w = (const float*)d_in[1];
  const float* conv1_b = (const float*)d_in[2];
  const float* pp_w    = (const float*)d_in[3];
  const float* pp_b    = (const float*)d_in[4];
  const float* pa_w    = (const float*)d_in[5];
  const float* pa_b    = (const float*)d_in[6];
  const float* dw1_w   = (const float*)d_in[7];
  const float* dw1_bu  = (const float*)d_in[8];
  const float* dw1_ba  = (const float*)d_in[9];
  const float* cc1_w   = (const float*)d_in[10];
  const float* cc1_bu  = (const float*)d_in[11];
  const float* cc1_ba  = (const float*)d_in[12];
  const float* dw2_w   = (const float*)d_in[13];
  const float* dw2_bu  = (const float*)d_in[14];
  const float* dw2_ba  = (const float*)d_in[15];
  const float* cc2_w   = (const float*)d_in[16];
  const float* cc2_bu  = (const float*)d_in[17];
  const float* cc2_ba  = (const float*)d_in[18];
  const float* cls_w   = (const float*)d_in[19];
  const float* cls_bu  = (const float*)d_in[20];
  const float* cls_ba  = (const float*)d_in[21];
  float* out = (float*)d_out;

  float* ws = (float*)d_ws;
  float* pose1 = ws;                  // [0, 3686400)          32*30*30*128
  float* a1    = ws + 3686400;        // [3686400, 3916800)    32*30*30*8
  float* pose2 = ws + 3916800;        // [3916800, 4838400)    32*15*15*128
  float* a2    = ws + 4838400;        // [4838400, 4896000)    32*15*15*8
  float* pose3 = ws;                  // [0, 1843200)          32*15*15*256
  float* a3    = ws + 1843200;        // 32*15*15*16
  float* pose4 = ws + 1958400;        // 32*8*8*256
  float* a4    = ws + 2482688;        // 32*8*8*16
  float* pose5 = ws + 2515456;        // 32*8*8*256
  float* a5    = ws + 3039744;        // 32*8*8*16

  stem_primary_kernel<<<28800, 128, 0, stream>>>(x, conv1_w, conv1_b,
                                                 pp_w, pp_b, pa_w, pa_b, pose1, a1);
  dw_caps_kernel<7, 8><<<57600 * 16 / 256, 256, 0, stream>>>(
      pose1, a1, dw1_w, dw1_bu, dw1_ba, pose2, a2, 30, 30, 15, 15);
  cc_em_kernel<8><<<7200, 256, 0, stream>>>(pose2, a2, cc1_w, cc1_bu, cc1_ba, pose3, a3);
  dw_caps_kernel<5, 16><<<32768 * 16 / 256, 256, 0, stream>>>(
      pose3, a3, dw2_w, dw2_bu, dw2_ba, pose4, a4, 15, 15, 8, 8);
  cc_em_kernel<16><<<2048, 256, 0, stream>>>(pose4, a4, cc2_w, cc2_bu, cc2_ba, pose5, a5);
  cls_em_kernel<<<32, 640, 0, stream>>>(pose5, a5, cls_w, cls_bu, cls_ba, out);
}

// Round 6
// 323.939 us; speedup vs baseline: 2.4798x; 1.0921x over previous
//
#include <hip/hip_runtime.h>
#include <hip/hip_bf16.h>

#define EPS 1e-8f
#define LAMBDA 1e-3f
#define LN2PI_HALF 0.9189385332046727f

__device__ __forceinline__ float sigmoidf(float x) { return 1.f / (1.f + __expf(-x)); }

// ---------------------------------------------------------------------------
// 1) fused conv stem + primary caps. One 128-thread block per output position.
// ---------------------------------------------------------------------------
__global__ __launch_bounds__(128) void stem_primary_kernel(
    const float* __restrict__ x, const float* __restrict__ w,
    const float* __restrict__ bias,
    const float* __restrict__ wp, const float* __restrict__ bp,
    const float* __restrict__ wa, const float* __restrict__ ba,
    float* __restrict__ pose, float* __restrict__ a) {
  int idx = blockIdx.x;                 // b*900 + oi*30 + oj
  int oj = idx % 30;
  int oi = (idx / 30) % 30;
  int b  = idx / 900;
  int t  = threadIdx.x;
  __shared__ float xs[25];
  __shared__ float ys[64];
  if (t < 25) {
    int ki = t / 5, kj = t % 5;
    xs[t] = x[(b * 64 + 2 * oi + ki) * 64 + (2 * oj + kj)];
  }
  __syncthreads();
  if (t < 64) {
    float s = bias[t];
#pragma unroll
    for (int k = 0; k < 25; ++k) s += xs[k] * w[k * 64 + t];
    ys[t] = fmaxf(s, 0.f);
  }
  __syncthreads();
  float s = bp[t];
#pragma unroll 8
  for (int c = 0; c < 64; ++c) s += ys[c] * wp[c * 128 + t];
  pose[(size_t)idx * 128 + t] = s;
  if (t < 8) {
    float q = ba[t];
#pragma unroll 8
    for (int c = 0; c < 64; ++c) q += ys[c] * wa[c * 8 + t];
    a[(size_t)idx * 8 + t] = sigmoidf(q);
  }
}

// ---------------------------------------------------------------------------
// 2) depthwise caps (Cout=1 => EM degenerates to a single M-step; r == 1).
//    Single-pass moments: σ² = E[v²] − μ²(2−S).
// ---------------------------------------------------------------------------
template <int K, int BC>
__global__ __launch_bounds__(256) void dw_caps_kernel(
    const float* __restrict__ pose_in, const float* __restrict__ a_in,
    const float* __restrict__ Wt,
    const float* __restrict__ bu_p, const float* __restrict__ ba_p,
    float* __restrict__ pose_out, float* __restrict__ a_out,
    int Hin, int Win, int Hout, int Wout) {
  const int pad = K / 2;
  int tid = blockIdx.x * 256 + threadIdx.x;
  int p = tid & 15;
  int prob = tid >> 4;
  int c = prob % BC;
  int t1 = prob / BC;
  int oj = t1 % Wout; t1 /= Wout;
  int oi = t1 % Hout;
  int b = t1 / Hout;
  int ip = p >> 2, l = p & 3;

  int ih0 = 2 * oi - pad, iw0 = 2 * oj - pad;
  float rsum = 0.f, acc = 0.f, acc2 = 0.f;
#pragma unroll
  for (int ki = 0; ki < K; ++ki) {
    int ih = ih0 + ki;
    if (ih < 0 || ih >= Hin) continue;
    int rowbase = (b * Hin + ih) * Win;
#pragma unroll
    for (int kj = 0; kj < K; ++kj) {
      int iw = iw0 + kj;
      if (iw < 0 || iw >= Win) continue;
      int base = rowbase + iw;
      float ak = a_in[(size_t)base * BC + c];
      const float* pm = pose_in + ((size_t)base * BC + c) * 16 + ip * 4;
      const float* wr = Wt + ((ki * K + kj) * BC + c) * 16 + l;
      float v = pm[0] * wr[0] + pm[1] * wr[4] + pm[2] * wr[8] + pm[3] * wr[12];
      rsum += ak;
      float av = ak * v;
      acc += av;
      acc2 += av * v;
    }
  }
  float inv = 1.f / (rsum + EPS);
  float mu = acc * inv;
  float S = rsum * inv;
  float sg = acc2 * inv - mu * mu * (2.f - S);
  sg = fmaxf(sg, 0.f) + EPS;
  float hl = 0.5f * __logf(sg);
  float ls = hl;
  ls += __shfl_xor(ls, 1, 64);
  ls += __shfl_xor(ls, 2, 64);
  ls += __shfl_xor(ls, 4, 64);
  ls += __shfl_xor(ls, 8, 64);

  size_t obase = ((size_t)(b * Hout + oi) * Wout + oj) * BC + c;
  pose_out[obase * 16 + p] = mu;
  if (p == 0) {
    float cost = rsum * (16.f * bu_p[0] + ls);
    a_out[obase] = sigmoidf(LAMBDA * (ba_p[0] - cost));
  }
}

// ---------------------------------------------------------------------------
// 3) 1x1 conv caps with full 3-iter EM. COUT=16. One 256-thread block per
//    routing problem; votes/state in LDS. thread t -> (c = t/16, p = t%16).
// ---------------------------------------------------------------------------
template <int BIN>
__global__ __launch_bounds__(256) void cc_em_kernel(
    const float* __restrict__ pose_in, const float* __restrict__ a_arr,
    const float* __restrict__ Wt,
    const float* __restrict__ bu_p, const float* __restrict__ ba_p,
    float* __restrict__ pose_out, float* __restrict__ a_out) {
  constexpr int COUT = 16;
  __shared__ float pm_s[BIN * 16];
  __shared__ float ain_s[BIN];
  __shared__ float v_s[BIN][COUT * 16];
  __shared__ float rw_s[BIN][COUT];
  __shared__ float mu_s[COUT * 16];
  __shared__ float sg_s[COUT * 16];
  __shared__ float hl_s[COUT * 16];
  __shared__ float rsum_s[COUT];
  __shared__ float aout_s[COUT];
  __shared__ float lnap_s[BIN][COUT];

  int n = blockIdx.x, t = threadIdx.x;
  int c = t >> 4, p = t & 15;
  if (t < BIN * 16) pm_s[t] = pose_in[(size_t)n * BIN * 16 + t];
  if (t < BIN) ain_s[t] = a_arr[(size_t)n * BIN + t];
  __syncthreads();

  int ip = p >> 2, l = p & 3;
#pragma unroll
  for (int b = 0; b < BIN; ++b) {
    const float* wr = Wt + (b * COUT + c) * 16 + l;
    const float* pm = &pm_s[b * 16 + ip * 4];
    v_s[b][t] = pm[0] * wr[0] + pm[1] * wr[4] + pm[2] * wr[8] + pm[3] * wr[12];
  }
  if (t < BIN * COUT) rw_s[t / COUT][t % COUT] = (1.f / COUT) * ain_s[t / COUT];
  __syncthreads();

  for (int it = 0; it < 3; ++it) {
    if (t < COUT) {
      float s = 0.f;
#pragma unroll
      for (int b = 0; b < BIN; ++b) s += rw_s[b][t];
      rsum_s[t] = s;
    }
    __syncthreads();
    {
      float s = 0.f;
#pragma unroll
      for (int b = 0; b < BIN; ++b) s += rw_s[b][c] * v_s[b][t];
      float mu = s / (rsum_s[c] + EPS);
      mu_s[t] = mu;
      float s2 = 0.f;
#pragma unroll
      for (int b = 0; b < BIN; ++b) { float d = v_s[b][t] - mu; s2 += rw_s[b][c] * d * d; }
      float sg = s2 / (rsum_s[c] + EPS) + EPS;
      sg_s[t] = sg;
      hl_s[t] = 0.5f * __logf(sg);
    }
    __syncthreads();
    if (t < COUT) {
      float lsum = 0.f;
#pragma unroll
      for (int pp = 0; pp < 16; ++pp) lsum += hl_s[t * 16 + pp];
      float cost = rsum_s[t] * (16.f * bu_p[t] + lsum);
      aout_s[t] = sigmoidf(LAMBDA * (ba_p[t] - cost));
    }
    __syncthreads();
    if (it < 2) {
      if (t < BIN * COUT) {
        int b = t / COUT, cc = t % COUT;
        float s = __logf(EPS + aout_s[cc]) - 16.f * LN2PI_HALF;
#pragma unroll
        for (int pp = 0; pp < 16; ++pp) {
          float d = v_s[b][cc * 16 + pp] - mu_s[cc * 16 + pp];
          s += -d * d / (2.f * sg_s[cc * 16 + pp]) - hl_s[cc * 16 + pp];
        }
        lnap_s[b][cc] = s;
      }
      __syncthreads();
      if (t < BIN * COUT) {
        int b = t / COUT, cc = t % COUT;
        float m = -1e30f;
#pragma unroll
        for (int q = 0; q < COUT; ++q) m = fmaxf(m, lnap_s[b][q]);
        float Z = 0.f;
#pragma unroll
        for (int q = 0; q < COUT; ++q) Z += __expf(lnap_s[b][q] - m);
        rw_s[b][cc] = (__expf(lnap_s[b][cc] - m) / Z) * ain_s[b];
      }
      __syncthreads();
    }
  }
  pose_out[(size_t)n * COUT * 16 + t] = mu_s[t];
  if (t < COUT) a_out[(size_t)n * COUT + t] = aout_s[t];
}

// ---------------------------------------------------------------------------
// 4a) class caps M-step: one 256-thread block per (image b, capsule c).
//     Single-pass moments over 1024 b_in (4 per thread), wave butterfly +
//     LDS cross-wave reduce. Writes mu/inv2/base (+out on last call).
//     first!=0: rw = 0.1*a_in (iteration 0); else read X.
// ---------------------------------------------------------------------------
__global__ __launch_bounds__(256) void cls_m_kernel(
    const float* __restrict__ pose5, const float* __restrict__ a5,
    const float* __restrict__ X, const float* __restrict__ W,
    const float* __restrict__ bu_p, const float* __restrict__ ba_p,
    float* __restrict__ mu_g, float* __restrict__ inv2_g,
    float* __restrict__ base_g, float* __restrict__ out,
    int first, int last) {
  int blk = blockIdx.x;                 // b*10 + c
  int c = blk % 10, b = blk / 10;
  int t = threadIdx.x;
  int lane = t & 63, wv = t >> 6;
  const float* pg = pose5 + (size_t)b * 16384;
  __shared__ float w_s[16][16];         // [jj][d]
  {
    int d = t & 15, jj = t >> 4;
    w_s[jj][d] = W[(d * 10 + c) * 16 + jj];
  }
  __syncthreads();
  const int d = t & 15;
  float wf[16];
#pragma unroll
  for (int jj = 0; jj < 16; ++jj) wf[jj] = w_s[jj][d];

  float sA = 0.f, sV[16], sV2[16];
#pragma unroll
  for (int p = 0; p < 16; ++p) { sV[p] = 0.f; sV2[p] = 0.f; }
#pragma unroll
  for (int rep = 0; rep < 4; ++rep) {
    int bi = rep * 256 + t;
    int pos = bi >> 4;                  // (bi & 15) == d
    float rw = first ? 0.1f * a5[(size_t)b * 1024 + bi]
                     : X[(size_t)blk * 1024 + bi];
    float ci = (float)(pos >> 3) * 0.125f;
    float cj = (float)(pos & 7) * 0.125f;
    const float* pp = pg + pos * 256 + d * 16;
    float pmr[16];
#pragma unroll
    for (int q = 0; q < 16; ++q) pmr[q] = pp[q];
    sA += rw;
#pragma unroll
    for (int p = 0; p < 16; ++p) {
      int ip = p >> 2, l = p & 3;
      float v = pmr[ip * 4 + 0] * wf[0 * 4 + l] + pmr[ip * 4 + 1] * wf[1 * 4 + l]
              + pmr[ip * 4 + 2] * wf[2 * 4 + l] + pmr[ip * 4 + 3] * wf[3 * 4 + l];
      if (p == 0) v += ci;
      else if (p == 1) v += cj;
      float rv = rw * v;
      sV[p] += rv;
      sV2[p] += rv * v;
    }
  }
#pragma unroll
  for (int off = 1; off < 64; off <<= 1) {
    sA += __shfl_xor(sA, off, 64);
#pragma unroll
    for (int p = 0; p < 16; ++p) {
      sV[p]  += __shfl_xor(sV[p],  off, 64);
      sV2[p] += __shfl_xor(sV2[p], off, 64);
    }
  }
  __shared__ float red[4][36];          // 33 used, padded
  if (lane == 0) {
    red[wv][0] = sA;
#pragma unroll
    for (int p = 0; p < 16; ++p) { red[wv][1 + p] = sV[p]; red[wv][17 + p] = sV2[p]; }
  }
  __syncthreads();
  if (t < 16) {
    int p = t;
    float sAf  = red[0][0] + red[1][0] + red[2][0] + red[3][0];
    float sVf  = red[0][1+p] + red[1][1+p] + red[2][1+p] + red[3][1+p];
    float sV2f = red[0][17+p] + red[1][17+p] + red[2][17+p] + red[3][17+p];
    float inv = 1.f / (sAf + EPS);
    float S = sAf * inv;
    float mu = sVf * inv;
    float sg = sV2f * inv - mu * mu * (2.f - S) + EPS;
    sg = fmaxf(sg, EPS);
    mu_g[blk * 16 + p] = mu;
    inv2_g[blk * 16 + p] = 0.5f / sg;
    float hl = 0.5f * __logf(sg);
    float lsum = hl;
    lsum += __shfl_xor(lsum, 1, 64);
    lsum += __shfl_xor(lsum, 2, 64);
    lsum += __shfl_xor(lsum, 4, 64);
    lsum += __shfl_xor(lsum, 8, 64);
    if (p == 0) {
      float cost = sAf * (16.f * bu_p[c] + lsum);
      float ao = sigmoidf(LAMBDA * (ba_p[c] - cost));
      base_g[blk] = __logf(EPS + ao) - lsum - 16.f * LN2PI_HALF;
      if (last) out[blk] = ao;
    }
  }
}

// ---------------------------------------------------------------------------
// 4b) class caps E-step: 2 blocks of 512 per image; thread = one b_in.
//     Reads mu/inv2/base, recomputes votes, softmax over 10 capsules,
//     writes X = r*a_in.
// ---------------------------------------------------------------------------
__global__ __launch_bounds__(512) void cls_e_kernel(
    const float* __restrict__ pose5, const float* __restrict__ a5,
    const float* __restrict__ W,
    const float* __restrict__ mu_g, const float* __restrict__ inv2_g,
    const float* __restrict__ base_g, float* __restrict__ X) {
  int b = blockIdx.x >> 1;
  int t = threadIdx.x;
  int bi = ((blockIdx.x & 1) << 9) + t;
  const float* pg = pose5 + (size_t)b * 16384;
  __shared__ float w2[10][16][16];      // [c][jj][d]
  __shared__ float mu_s[160];
  __shared__ float inv2_s[160];
  __shared__ float base_s[10];
  for (int q = t; q < 2560; q += 512) {
    int dd = q & 15, jj = (q >> 4) & 15, c = q >> 8;
    w2[c][jj][dd] = W[(dd * 10 + c) * 16 + jj];
  }
  if (t < 160) { mu_s[t] = mu_g[b * 160 + t]; inv2_s[t] = inv2_g[b * 160 + t]; }
  if (t >= 160 && t < 170) base_s[t - 160] = base_g[b * 10 + (t - 160)];
  __syncthreads();

  int pos = bi >> 4, d2 = bi & 15;
  float ci = (float)(pos >> 3) * 0.125f;
  float cj = (float)(pos & 7) * 0.125f;
  const float* pp = pg + pos * 256 + d2 * 16;
  float pmr[16];
#pragma unroll
  for (int q = 0; q < 16; ++q) pmr[q] = pp[q];
  float lnap[10];
#pragma unroll
  for (int c = 0; c < 10; ++c) {
    float wf[16];
#pragma unroll
    for (int jj = 0; jj < 16; ++jj) wf[jj] = w2[c][jj][d2];
    float s = base_s[c];
#pragma unroll
    for (int p = 0; p < 16; ++p) {
      int ip = p >> 2, l = p & 3;
      float v = pmr[ip * 4 + 0] * wf[0 * 4 + l] + pmr[ip * 4 + 1] * wf[1 * 4 + l]
              + pmr[ip * 4 + 2] * wf[2 * 4 + l] + pmr[ip * 4 + 3] * wf[3 * 4 + l];
      if (p == 0) v += ci;
      else if (p == 1) v += cj;
      float dd = v - mu_s[c * 16 + p];
      s -= dd * dd * inv2_s[c * 16 + p];
    }
    lnap[c] = s;
  }
  float m = -1e30f;
#pragma unroll
  for (int c = 0; c < 10; ++c) m = fmaxf(m, lnap[c]);
  float Z = 0.f;
  float ex[10];
#pragma unroll
  for (int c = 0; c < 10; ++c) { ex[c] = __expf(lnap[c] - m); Z += ex[c]; }
  float invZ = a5[(size_t)b * 1024 + bi] / Z;
#pragma unroll
  for (int c = 0; c < 10; ++c) X[((size_t)(b * 10 + c)) * 1024 + bi] = ex[c] * invZ;
}

// ---------------------------------------------------------------------------
extern "C" void kernel_launch(void* const* d_in, const int* in_sizes, int n_in,
                              void* d_out, int out_size, void* d_ws, size_t ws_size,
                              hipStream_t stream) {
  const float* x       = (const float*)d_in[0];
  const float* conv1_w = (const float*)d_in[1];
  const float* conv1_b = (const float*)d_in[2];
  const float* pp_w    = (const float*)d_in[3];
  const float* pp_b    = (const float*)d_in[4];
  const float* pa_w    = (const float*)d_in[5];
  const float* pa_b    = (const float*)d_in[6];
  const float* dw1_w   = (const float*)d_in[7];
  const float* dw1_bu  = (const float*)d_in[8];
  const float* dw1_ba  = (const float*)d_in[9];
  const float* cc1_w   = (const float*)d_in[10];
  const float* cc1_bu  = (const float*)d_in[11];
  const float* cc1_ba  = (const float*)d_in[12];
  const float* dw2_w   = (const float*)d_in[13];
  const float* dw2_bu  = (const float*)d_in[14];
  const float* dw2_ba  = (const float*)d_in[15];
  const float* cc2_w   = (const float*)d_in[16];
  const float* cc2_bu  = (const float*)d_in[17];
  const float* cc2_ba  = (const float*)d_in[18];
  const float* cls_w   = (const float*)d_in[19];
  const float* cls_bu  = (const float*)d_in[20];
  const float* cls_ba  = (const float*)d_in[21];
  float* out = (float*)d_out;

  float* ws = (float*)d_ws;
  float* pose1 = ws;                  // [0, 3686400)          32*30*30*128
  float* a1    = ws + 3686400;        // [3686400, 3916800)    32*30*30*8
  float* pose2 = ws + 3916800;        // [3916800, 4838400)    32*15*15*128
  float* a2    = ws + 4838400;        // [4838400, 4896000)    32*15*15*8
  float* pose3 = ws;                  // [0, 1843200)          32*15*15*256
  float* a3    = ws + 1843200;        // 32*15*15*16
  float* pose4 = ws + 1958400;        // 32*8*8*256
  float* a4    = ws + 2482688;        // 32*8*8*16
  float* pose5 = ws + 2515456;        // 32*8*8*256
  float* a5    = ws + 3039744;        // 32*8*8*16
  float* Xbuf  = ws + 3072512;        // 32*10*1024 = 327680
  float* mu_g  = ws + 3400192;        // 32*160
  float* inv2_g= ws + 3405312;        // 32*160
  float* base_g= ws + 3410432;        // 32*10   (ends 3410752 < 3916800)

  stem_primary_kernel<<<28800, 128, 0, stream>>>(x, conv1_w, conv1_b,
                                                 pp_w, pp_b, pa_w, pa_b, pose1, a1);
  dw_caps_kernel<7, 8><<<57600 * 16 / 256, 256, 0, stream>>>(
      pose1, a1, dw1_w, dw1_bu, dw1_ba, pose2, a2, 30, 30, 15, 15);
  cc_em_kernel<8><<<7200, 256, 0, stream>>>(pose2, a2, cc1_w, cc1_bu, cc1_ba, pose3, a3);
  dw_caps_kernel<5, 16><<<32768 * 16 / 256, 256, 0, stream>>>(
      pose3, a3, dw2_w, dw2_bu, dw2_ba, pose4, a4, 15, 15, 8, 8);
  cc_em_kernel<16><<<2048, 256, 0, stream>>>(pose4, a4, cc2_w, cc2_bu, cc2_ba, pose5, a5);
  // class caps EM: M,E,M,E,M across 320/64-block dispatches
  cls_m_kernel<<<320, 256, 0, stream>>>(pose5, a5, Xbuf, cls_w, cls_bu, cls_ba,
                                        mu_g, inv2_g, base_g, out, 1, 0);
  cls_e_kernel<<<64, 512, 0, stream>>>(pose5, a5, cls_w, mu_g, inv2_g, base_g, Xbuf);
  cls_m_kernel<<<320, 256, 0, stream>>>(pose5, a5, Xbuf, cls_w, cls_bu, cls_ba,
                                        mu_g, inv2_g, base_g, out, 0, 0);
  cls_e_kernel<<<64, 512, 0, stream>>>(pose5, a5, cls_w, mu_g, inv2_g, base_g, Xbuf);
  cls_m_kernel<<<320, 256, 0, stream>>>(pose5, a5, Xbuf, cls_w, cls_bu, cls_ba,
                                        mu_g, inv2_g, base_g, out, 0, 1);
}

// Round 7
// 302.829 us; speedup vs baseline: 2.6527x; 1.0697x over previous
//
#include <hip/hip_runtime.h>
#include <hip/hip_bf16.h>

#define EPS 1e-8f
#define LAMBDA 1e-3f
#define LN2PI_HALF 0.9189385332046727f

__device__ __forceinline__ float sigmoidf(float x) { return 1.f / (1.f + __expf(-x)); }

// ---------------------------------------------------------------------------
// 1) fused conv stem + primary caps, TILED. One 256-thread block per 10
//    consecutive oj at fixed (b,oi). All weights staged in LDS once per block
//    (was: every position-block re-read 32KB wp from L2 -> ~920MB traffic).
//    grid = 32*30*3 = 2880.
// ---------------------------------------------------------------------------
__global__ __launch_bounds__(256) void stem_primary_kernel(
    const float* __restrict__ x, const float* __restrict__ w,
    const float* __restrict__ bias,
    const float* __restrict__ wp, const float* __restrict__ bp,
    const float* __restrict__ wa, const float* __restrict__ ba,
    float* __restrict__ pose, float* __restrict__ a) {
  __shared__ float wp_s[64][128];   // 32 KB
  __shared__ float wc_s[25][64];    // 6.4 KB
  __shared__ float wa_s[64][8];     // 2 KB
  __shared__ float bias_s[64];
  __shared__ float bp_s[128];
  __shared__ float ba_s[8];
  __shared__ float xs[5][23];       // input patch: 5 rows x (2*9+5) cols
  __shared__ float ys[10][64];      // conv outputs for the 10 positions

  int t = threadIdx.x;
  int jt = blockIdx.x % 3;
  int oi = (blockIdx.x / 3) % 30;
  int b  = blockIdx.x / 90;
  int oj0 = jt * 10;

  for (int q = t; q < 8192; q += 256) ((float*)wp_s)[q] = wp[q];
  for (int q = t; q < 1600; q += 256) ((float*)wc_s)[q] = w[q];
  for (int q = t; q < 512;  q += 256) ((float*)wa_s)[q] = wa[q];
  if (t < 64) bias_s[t] = bias[t];
  if (t < 128) bp_s[t] = bp[t];
  if (t < 8) ba_s[t] = ba[t];
  for (int q = t; q < 115; q += 256) {
    int ki = q / 23, kj = q % 23;
    xs[ki][kj] = x[(b * 64 + 2 * oi + ki) * 64 + 2 * oj0 + kj];
  }
  __syncthreads();

  // conv: 10 pos x 64 ch
#pragma unroll
  for (int rep = 0; rep < 3; ++rep) {
    int q = rep * 256 + t;
    if (q < 640) {
      int pos = q >> 6, ch = q & 63;
      float s = bias_s[ch];
#pragma unroll
      for (int ki = 0; ki < 5; ++ki)
#pragma unroll
        for (int kj = 0; kj < 5; ++kj)
          s += xs[ki][2 * pos + kj] * wc_s[ki * 5 + kj][ch];
      ys[pos][ch] = fmaxf(s, 0.f);
    }
  }
  __syncthreads();

  // pose: thread handles d = t&127 for 5 positions (w_ + 2j)
  int w_ = t >> 7, d = t & 127;
  float acc[5];
#pragma unroll
  for (int j = 0; j < 5; ++j) acc[j] = bp_s[d];
  for (int c = 0; c < 64; ++c) {
    float wv = wp_s[c][d];
#pragma unroll
    for (int j = 0; j < 5; ++j) acc[j] += ys[w_ + 2 * j][c] * wv;
  }
  size_t rowbase = (size_t)(b * 30 + oi) * 30 + oj0;
#pragma unroll
  for (int j = 0; j < 5; ++j)
    pose[(rowbase + w_ + 2 * j) * 128 + d] = acc[j];

  // activations: 10 pos x 8
  if (t < 80) {
    int pos = t >> 3, jj = t & 7;
    float s = ba_s[jj];
#pragma unroll 8
    for (int c = 0; c < 64; ++c) s += ys[pos][c] * wa_s[c][jj];
    a[(rowbase + pos) * 8 + jj] = sigmoidf(s);
  }
}

// ---------------------------------------------------------------------------
// 2) depthwise caps (Cout=1 => single M-step; r == 1). Single-pass moments.
//    Dims are TEMPLATE constants + interior fast path (no per-tap bounds
//    checks, fully unrolled load stream) — was VGPR=20, latency-bound.
// ---------------------------------------------------------------------------
template <int K, int BC, int HIN, int WIN, int HOUT, int WOUT>
__global__ __launch_bounds__(256) void dw_caps_kernel(
    const float* __restrict__ pose_in, const float* __restrict__ a_in,
    const float* __restrict__ Wt,
    const float* __restrict__ bu_p, const float* __restrict__ ba_p,
    float* __restrict__ pose_out, float* __restrict__ a_out) {
  constexpr int PAD = K / 2;
  int tid = blockIdx.x * 256 + threadIdx.x;
  int p = tid & 15;
  int prob = tid >> 4;
  int c = prob % BC;
  int t1 = prob / BC;
  int oj = t1 % WOUT; t1 /= WOUT;
  int oi = t1 % HOUT;
  int b = t1 / HOUT;
  int ip = p >> 2, l = p & 3;

  int ih0 = 2 * oi - PAD, iw0 = 2 * oj - PAD;
  float rsum = 0.f, acc = 0.f, acc2 = 0.f;

  if (ih0 >= 0 && ih0 + K <= HIN && iw0 >= 0 && iw0 + K <= WIN) {
#pragma unroll
    for (int ki = 0; ki < K; ++ki) {
      int rowbase = (b * HIN + ih0 + ki) * WIN + iw0;
#pragma unroll
      for (int kj = 0; kj < K; ++kj) {
        int base = rowbase + kj;
        float ak = a_in[(size_t)base * BC + c];
        const float* pm = pose_in + ((size_t)base * BC + c) * 16 + ip * 4;
        const float* wr = Wt + ((ki * K + kj) * BC + c) * 16 + l;
        float v = pm[0] * wr[0] + pm[1] * wr[4] + pm[2] * wr[8] + pm[3] * wr[12];
        rsum += ak;
        float av = ak * v;
        acc += av;
        acc2 += av * v;
      }
    }
  } else {
#pragma unroll
    for (int ki = 0; ki < K; ++ki) {
      int ih = ih0 + ki;
      if (ih < 0 || ih >= HIN) continue;
      int rowbase = (b * HIN + ih) * WIN;
#pragma unroll
      for (int kj = 0; kj < K; ++kj) {
        int iw = iw0 + kj;
        if (iw < 0 || iw >= WIN) continue;
        int base = rowbase + iw;
        float ak = a_in[(size_t)base * BC + c];
        const float* pm = pose_in + ((size_t)base * BC + c) * 16 + ip * 4;
        const float* wr = Wt + ((ki * K + kj) * BC + c) * 16 + l;
        float v = pm[0] * wr[0] + pm[1] * wr[4] + pm[2] * wr[8] + pm[3] * wr[12];
        rsum += ak;
        float av = ak * v;
        acc += av;
        acc2 += av * v;
      }
    }
  }
  float inv = 1.f / (rsum + EPS);
  float mu = acc * inv;
  float S = rsum * inv;
  float sg = acc2 * inv - mu * mu * (2.f - S);
  sg = fmaxf(sg, 0.f) + EPS;
  float hl = 0.5f * __logf(sg);
  float ls = hl;
  ls += __shfl_xor(ls, 1, 64);
  ls += __shfl_xor(ls, 2, 64);
  ls += __shfl_xor(ls, 4, 64);
  ls += __shfl_xor(ls, 8, 64);

  size_t obase = ((size_t)(b * HOUT + oi) * WOUT + oj) * BC + c;
  pose_out[obase * 16 + p] = mu;
  if (p == 0) {
    float cost = rsum * (16.f * bu_p[0] + ls);
    a_out[obase] = sigmoidf(LAMBDA * (ba_p[0] - cost));
  }
}

// ---------------------------------------------------------------------------
// 3) 1x1 conv caps with full 3-iter EM. COUT=16. One 256-thread block per
//    routing problem; votes/state in LDS. thread t -> (c = t/16, p = t%16).
// ---------------------------------------------------------------------------
template <int BIN>
__global__ __launch_bounds__(256) void cc_em_kernel(
    const float* __restrict__ pose_in, const float* __restrict__ a_arr,
    const float* __restrict__ Wt,
    const float* __restrict__ bu_p, const float* __restrict__ ba_p,
    float* __restrict__ pose_out, float* __restrict__ a_out) {
  constexpr int COUT = 16;
  __shared__ float pm_s[BIN * 16];
  __shared__ float ain_s[BIN];
  __shared__ float v_s[BIN][COUT * 16];
  __shared__ float rw_s[BIN][COUT];
  __shared__ float mu_s[COUT * 16];
  __shared__ float sg_s[COUT * 16];
  __shared__ float hl_s[COUT * 16];
  __shared__ float rsum_s[COUT];
  __shared__ float aout_s[COUT];
  __shared__ float lnap_s[BIN][COUT];

  int n = blockIdx.x, t = threadIdx.x;
  int c = t >> 4, p = t & 15;
  if (t < BIN * 16) pm_s[t] = pose_in[(size_t)n * BIN * 16 + t];
  if (t < BIN) ain_s[t] = a_arr[(size_t)n * BIN + t];
  __syncthreads();

  int ip = p >> 2, l = p & 3;
#pragma unroll
  for (int b = 0; b < BIN; ++b) {
    const float* wr = Wt + (b * COUT + c) * 16 + l;
    const float* pm = &pm_s[b * 16 + ip * 4];
    v_s[b][t] = pm[0] * wr[0] + pm[1] * wr[4] + pm[2] * wr[8] + pm[3] * wr[12];
  }
  if (t < BIN * COUT) rw_s[t / COUT][t % COUT] = (1.f / COUT) * ain_s[t / COUT];
  __syncthreads();

  for (int it = 0; it < 3; ++it) {
    if (t < COUT) {
      float s = 0.f;
#pragma unroll
      for (int b = 0; b < BIN; ++b) s += rw_s[b][t];
      rsum_s[t] = s;
    }
    __syncthreads();
    {
      float s = 0.f;
#pragma unroll
      for (int b = 0; b < BIN; ++b) s += rw_s[b][c] * v_s[b][t];
      float mu = s / (rsum_s[c] + EPS);
      mu_s[t] = mu;
      float s2 = 0.f;
#pragma unroll
      for (int b = 0; b < BIN; ++b) { float d = v_s[b][t] - mu; s2 += rw_s[b][c] * d * d; }
      float sg = s2 / (rsum_s[c] + EPS) + EPS;
      sg_s[t] = sg;
      hl_s[t] = 0.5f * __logf(sg);
    }
    __syncthreads();
    if (t < COUT) {
      float lsum = 0.f;
#pragma unroll
      for (int pp = 0; pp < 16; ++pp) lsum += hl_s[t * 16 + pp];
      float cost = rsum_s[t] * (16.f * bu_p[t] + lsum);
      aout_s[t] = sigmoidf(LAMBDA * (ba_p[t] - cost));
    }
    __syncthreads();
    if (it < 2) {
      if (t < BIN * COUT) {
        int b = t / COUT, cc = t % COUT;
        float s = __logf(EPS + aout_s[cc]) - 16.f * LN2PI_HALF;
#pragma unroll
        for (int pp = 0; pp < 16; ++pp) {
          float d = v_s[b][cc * 16 + pp] - mu_s[cc * 16 + pp];
          s += -d * d / (2.f * sg_s[cc * 16 + pp]) - hl_s[cc * 16 + pp];
        }
        lnap_s[b][cc] = s;
      }
      __syncthreads();
      if (t < BIN * COUT) {
        int b = t / COUT, cc = t % COUT;
        float m = -1e30f;
#pragma unroll
        for (int q = 0; q < COUT; ++q) m = fmaxf(m, lnap_s[b][q]);
        float Z = 0.f;
#pragma unroll
        for (int q = 0; q < COUT; ++q) Z += __expf(lnap_s[b][q] - m);
        rw_s[b][cc] = (__expf(lnap_s[b][cc] - m) / Z) * ain_s[b];
      }
      __syncthreads();
    }
  }
  pose_out[(size_t)n * COUT * 16 + t] = mu_s[t];
  if (t < COUT) a_out[(size_t)n * COUT + t] = aout_s[t];
}

// ---------------------------------------------------------------------------
// 4a) class caps M-step: one 256-thread block per (image b, capsule c).
// ---------------------------------------------------------------------------
__global__ __launch_bounds__(256) void cls_m_kernel(
    const float* __restrict__ pose5, const float* __restrict__ a5,
    const float* __restrict__ X, const float* __restrict__ W,
    const float* __restrict__ bu_p, const float* __restrict__ ba_p,
    float* __restrict__ mu_g, float* __restrict__ inv2_g,
    float* __restrict__ base_g, float* __restrict__ out,
    int first, int last) {
  int blk = blockIdx.x;                 // b*10 + c
  int c = blk % 10, b = blk / 10;
  int t = threadIdx.x;
  int lane = t & 63, wv = t >> 6;
  const float* pg = pose5 + (size_t)b * 16384;
  __shared__ float w_s[16][16];         // [jj][d]
  {
    int d = t & 15, jj = t >> 4;
    w_s[jj][d] = W[(d * 10 + c) * 16 + jj];
  }
  __syncthreads();
  const int d = t & 15;
  float wf[16];
#pragma unroll
  for (int jj = 0; jj < 16; ++jj) wf[jj] = w_s[jj][d];

  float sA = 0.f, sV[16], sV2[16];
#pragma unroll
  for (int p = 0; p < 16; ++p) { sV[p] = 0.f; sV2[p] = 0.f; }
#pragma unroll
  for (int rep = 0; rep < 4; ++rep) {
    int bi = rep * 256 + t;
    int pos = bi >> 4;                  // (bi & 15) == d
    float rw = first ? 0.1f * a5[(size_t)b * 1024 + bi]
                     : X[(size_t)blk * 1024 + bi];
    float ci = (float)(pos >> 3) * 0.125f;
    float cj = (float)(pos & 7) * 0.125f;
    const float* pp = pg + pos * 256 + d * 16;
    float pmr[16];
#pragma unroll
    for (int q = 0; q < 16; ++q) pmr[q] = pp[q];
    sA += rw;
#pragma unroll
    for (int p = 0; p < 16; ++p) {
      int ip = p >> 2, l = p & 3;
      float v = pmr[ip * 4 + 0] * wf[0 * 4 + l] + pmr[ip * 4 + 1] * wf[1 * 4 + l]
              + pmr[ip * 4 + 2] * wf[2 * 4 + l] + pmr[ip * 4 + 3] * wf[3 * 4 + l];
      if (p == 0) v += ci;
      else if (p == 1) v += cj;
      float rv = rw * v;
      sV[p] += rv;
      sV2[p] += rv * v;
    }
  }
#pragma unroll
  for (int off = 1; off < 64; off <<= 1) {
    sA += __shfl_xor(sA, off, 64);
#pragma unroll
    for (int p = 0; p < 16; ++p) {
      sV[p]  += __shfl_xor(sV[p],  off, 64);
      sV2[p] += __shfl_xor(sV2[p], off, 64);
    }
  }
  __shared__ float red[4][36];
  if (lane == 0) {
    red[wv][0] = sA;
#pragma unroll
    for (int p = 0; p < 16; ++p) { red[wv][1 + p] = sV[p]; red[wv][17 + p] = sV2[p]; }
  }
  __syncthreads();
  if (t < 16) {
    int p = t;
    float sAf  = red[0][0] + red[1][0] + red[2][0] + red[3][0];
    float sVf  = red[0][1+p] + red[1][1+p] + red[2][1+p] + red[3][1+p];
    float sV2f = red[0][17+p] + red[1][17+p] + red[2][17+p] + red[3][17+p];
    float inv = 1.f / (sAf + EPS);
    float S = sAf * inv;
    float mu = sVf * inv;
    float sg = sV2f * inv - mu * mu * (2.f - S) + EPS;
    sg = fmaxf(sg, EPS);
    mu_g[blk * 16 + p] = mu;
    inv2_g[blk * 16 + p] = 0.5f / sg;
    float hl = 0.5f * __logf(sg);
    float lsum = hl;
    lsum += __shfl_xor(lsum, 1, 64);
    lsum += __shfl_xor(lsum, 2, 64);
    lsum += __shfl_xor(lsum, 4, 64);
    lsum += __shfl_xor(lsum, 8, 64);
    if (p == 0) {
      float cost = sAf * (16.f * bu_p[c] + lsum);
      float ao = sigmoidf(LAMBDA * (ba_p[c] - cost));
      base_g[blk] = __logf(EPS + ao) - lsum - 16.f * LN2PI_HALF;
      if (last) out[blk] = ao;
    }
  }
}

// ---------------------------------------------------------------------------
// 4b) class caps E-step: 2 blocks of 512 per image; thread = one b_in.
// ---------------------------------------------------------------------------
__global__ __launch_bounds__(512) void cls_e_kernel(
    const float* __restrict__ pose5, const float* __restrict__ a5,
    const float* __restrict__ W,
    const float* __restrict__ mu_g, const float* __restrict__ inv2_g,
    const float* __restrict__ base_g, float* __restrict__ X) {
  int b = blockIdx.x >> 1;
  int t = threadIdx.x;
  int bi = ((blockIdx.x & 1) << 9) + t;
  const float* pg = pose5 + (size_t)b * 16384;
  __shared__ float w2[10][16][16];      // [c][jj][d]
  __shared__ float mu_s[160];
  __shared__ float inv2_s[160];
  __shared__ float base_s[10];
  for (int q = t; q < 2560; q += 512) {
    int dd = q & 15, jj = (q >> 4) & 15, c = q >> 8;
    w2[c][jj][dd] = W[(dd * 10 + c) * 16 + jj];
  }
  if (t < 160) { mu_s[t] = mu_g[b * 160 + t]; inv2_s[t] = inv2_g[b * 160 + t]; }
  if (t >= 160 && t < 170) base_s[t - 160] = base_g[b * 10 + (t - 160)];
  __syncthreads();

  int pos = bi >> 4, d2 = bi & 15;
  float ci = (float)(pos >> 3) * 0.125f;
  float cj = (float)(pos & 7) * 0.125f;
  const float* pp = pg + pos * 256 + d2 * 16;
  float pmr[16];
#pragma unroll
  for (int q = 0; q < 16; ++q) pmr[q] = pp[q];
  float lnap[10];
#pragma unroll
  for (int c = 0; c < 10; ++c) {
    float wf[16];
#pragma unroll
    for (int jj = 0; jj < 16; ++jj) wf[jj] = w2[c][jj][d2];
    float s = base_s[c];
#pragma unroll
    for (int p = 0; p < 16; ++p) {
      int ip = p >> 2, l = p & 3;
      float v = pmr[ip * 4 + 0] * wf[0 * 4 + l] + pmr[ip * 4 + 1] * wf[1 * 4 + l]
              + pmr[ip * 4 + 2] * wf[2 * 4 + l] + pmr[ip * 4 + 3] * wf[3 * 4 + l];
      if (p == 0) v += ci;
      else if (p == 1) v += cj;
      float dd = v - mu_s[c * 16 + p];
      s -= dd * dd * inv2_s[c * 16 + p];
    }
    lnap[c] = s;
  }
  float m = -1e30f;
#pragma unroll
  for (int c = 0; c < 10; ++c) m = fmaxf(m, lnap[c]);
  float Z = 0.f;
  float ex[10];
#pragma unroll
  for (int c = 0; c < 10; ++c) { ex[c] = __expf(lnap[c] - m); Z += ex[c]; }
  float invZ = a5[(size_t)b * 1024 + bi] / Z;
#pragma unroll
  for (int c = 0; c < 10; ++c) X[((size_t)(b * 10 + c)) * 1024 + bi] = ex[c] * invZ;
}

// ---------------------------------------------------------------------------
extern "C" void kernel_launch(void* const* d_in, const int* in_sizes, int n_in,
                              void* d_out, int out_size, void* d_ws, size_t ws_size,
                              hipStream_t stream) {
  const float* x       = (const float*)d_in[0];
  const float* conv1_w = (const float*)d_in[1];
  const float* conv1_b = (const float*)d_in[2];
  const float* pp_w    = (const float*)d_in[3];
  const float* pp_b    = (const float*)d_in[4];
  const float* pa_w    = (const float*)d_in[5];
  const float* pa_b    = (const float*)d_in[6];
  const float* dw1_w   = (const float*)d_in[7];
  const float* dw1_bu  = (const float*)d_in[8];
  const float* dw1_ba  = (const float*)d_in[9];
  const float* cc1_w   = (const float*)d_in[10];
  const float* cc1_bu  = (const float*)d_in[11];
  const float* cc1_ba  = (const float*)d_in[12];
  const float* dw2_w   = (const float*)d_in[13];
  const float* dw2_bu  = (const float*)d_in[14];
  const float* dw2_ba  = (const float*)d_in[15];
  const float* cc2_w   = (const float*)d_in[16];
  const float* cc2_bu  = (const float*)d_in[17];
  const float* cc2_ba  = (const float*)d_in[18];
  const float* cls_w   = (const float*)d_in[19];
  const float* cls_bu  = (const float*)d_in[20];
  const float* cls_ba  = (const float*)d_in[21];
  float* out = (float*)d_out;

  float* ws = (float*)d_ws;
  float* pose1 = ws;                  // [0, 3686400)          32*30*30*128
  float* a1    = ws + 3686400;        // 32*30*30*8
  float* pose2 = ws + 3916800;        // 32*15*15*128
  float* a2    = ws + 4838400;        // 32*15*15*8
  float* pose3 = ws;                  // 32*15*15*256 (aliases dead pose1)
  float* a3    = ws + 1843200;        // 32*15*15*16
  float* pose4 = ws + 1958400;        // 32*8*8*256
  float* a4    = ws + 2482688;        // 32*8*8*16
  float* pose5 = ws + 2515456;        // 32*8*8*256
  float* a5    = ws + 3039744;        // 32*8*8*16
  float* Xbuf  = ws + 3072512;        // 32*10*1024
  float* mu_g  = ws + 3400192;        // 32*160
  float* inv2_g= ws + 3405312;        // 32*160
  float* base_g= ws + 3410432;        // 32*10

  stem_primary_kernel<<<2880, 256, 0, stream>>>(x, conv1_w, conv1_b,
                                                pp_w, pp_b, pa_w, pa_b, pose1, a1);
  dw_caps_kernel<7, 8, 30, 30, 15, 15><<<3600, 256, 0, stream>>>(
      pose1, a1, dw1_w, dw1_bu, dw1_ba, pose2, a2);
  cc_em_kernel<8><<<7200, 256, 0, stream>>>(pose2, a2, cc1_w, cc1_bu, cc1_ba, pose3, a3);
  dw_caps_kernel<5, 16, 15, 15, 8, 8><<<2048, 256, 0, stream>>>(
      pose3, a3, dw2_w, dw2_bu, dw2_ba, pose4, a4);
  cc_em_kernel<16><<<2048, 256, 0, stream>>>(pose4, a4, cc2_w, cc2_bu, cc2_ba, pose5, a5);
  cls_m_kernel<<<320, 256, 0, stream>>>(pose5, a5, Xbuf, cls_w, cls_bu, cls_ba,
                                        mu_g, inv2_g, base_g, out, 1, 0);
  cls_e_kernel<<<64, 512, 0, stream>>>(pose5, a5, cls_w, mu_g, inv2_g, base_g, Xbuf);
  cls_m_kernel<<<320, 256, 0, stream>>>(pose5, a5, Xbuf, cls_w, cls_bu, cls_ba,
                                        mu_g, inv2_g, base_g, out, 0, 0);
  cls_e_kernel<<<64, 512, 0, stream>>>(pose5, a5, cls_w, mu_g, inv2_g, base_g, Xbuf);
  cls_m_kernel<<<320, 256, 0, stream>>>(pose5, a5, Xbuf, cls_w, cls_bu, cls_ba,
                                        mu_g, inv2_g, base_g, out, 0, 1);
}

// Round 8
// 286.242 us; speedup vs baseline: 2.8064x; 1.0579x over previous
//
#include <hip/hip_runtime.h>
#include <hip/hip_bf16.h>

#define EPS 1e-8f
#define LAMBDA 1e-3f
#define LN2PI_HALF 0.9189385332046727f

__device__ __forceinline__ float sigmoidf(float x) { return 1.f / (1.f + __expf(-x)); }

// ---------------------------------------------------------------------------
// 1) fused conv stem + primary caps, TILED. One 256-thread block per 10
//    consecutive oj at fixed (b,oi). All weights staged in LDS once per block.
// ---------------------------------------------------------------------------
__global__ __launch_bounds__(256) void stem_primary_kernel(
    const float* __restrict__ x, const float* __restrict__ w,
    const float* __restrict__ bias,
    const float* __restrict__ wp, const float* __restrict__ bp,
    const float* __restrict__ wa, const float* __restrict__ ba,
    float* __restrict__ pose, float* __restrict__ a) {
  __shared__ float wp_s[64][128];   // 32 KB
  __shared__ float wc_s[25][64];    // 6.4 KB
  __shared__ float wa_s[64][8];     // 2 KB
  __shared__ float bias_s[64];
  __shared__ float bp_s[128];
  __shared__ float ba_s[8];
  __shared__ float xs[5][23];
  __shared__ float ys[10][64];

  int t = threadIdx.x;
  int jt = blockIdx.x % 3;
  int oi = (blockIdx.x / 3) % 30;
  int b  = blockIdx.x / 90;
  int oj0 = jt * 10;

  for (int q = t; q < 8192; q += 256) ((float*)wp_s)[q] = wp[q];
  for (int q = t; q < 1600; q += 256) ((float*)wc_s)[q] = w[q];
  for (int q = t; q < 512;  q += 256) ((float*)wa_s)[q] = wa[q];
  if (t < 64) bias_s[t] = bias[t];
  if (t < 128) bp_s[t] = bp[t];
  if (t < 8) ba_s[t] = ba[t];
  for (int q = t; q < 115; q += 256) {
    int ki = q / 23, kj = q % 23;
    xs[ki][kj] = x[(b * 64 + 2 * oi + ki) * 64 + 2 * oj0 + kj];
  }
  __syncthreads();

#pragma unroll
  for (int rep = 0; rep < 3; ++rep) {
    int q = rep * 256 + t;
    if (q < 640) {
      int pos = q >> 6, ch = q & 63;
      float s = bias_s[ch];
#pragma unroll
      for (int ki = 0; ki < 5; ++ki)
#pragma unroll
        for (int kj = 0; kj < 5; ++kj)
          s += xs[ki][2 * pos + kj] * wc_s[ki * 5 + kj][ch];
      ys[pos][ch] = fmaxf(s, 0.f);
    }
  }
  __syncthreads();

  int w_ = t >> 7, d = t & 127;
  float acc[5];
#pragma unroll
  for (int j = 0; j < 5; ++j) acc[j] = bp_s[d];
  for (int c = 0; c < 64; ++c) {
    float wv = wp_s[c][d];
#pragma unroll
    for (int j = 0; j < 5; ++j) acc[j] += ys[w_ + 2 * j][c] * wv;
  }
  size_t rowbase = (size_t)(b * 30 + oi) * 30 + oj0;
#pragma unroll
  for (int j = 0; j < 5; ++j)
    pose[(rowbase + w_ + 2 * j) * 128 + d] = acc[j];

  if (t < 80) {
    int pos = t >> 3, jj = t & 7;
    float s = ba_s[jj];
#pragma unroll 8
    for (int c = 0; c < 64; ++c) s += ys[pos][c] * wa_s[c][jj];
    a[(rowbase + pos) * 8 + jj] = sigmoidf(s);
  }
}

// ---------------------------------------------------------------------------
// 2) depthwise caps v3 — LDS-TILED. Block = (b, capsule c, oi-group g).
//    Stage pose tile (stride 20 floats, 16B-aligned), a tile, and this c's
//    weights TRANSPOSED to [tap][l][j] (contiguous b128 read in compute).
//    Tap loop runs entirely from LDS. Was: 6 global loads/tap, 4x-redundant
//    pose reads, VGPR=28 latency-bound, 54 us.
// ---------------------------------------------------------------------------
template <int K, int BC, int HIN, int WIN, int HOUT, int WOUT, int OIG, int NG>
__global__ __launch_bounds__(256) void dw_caps_kernel(
    const float* __restrict__ pose_in, const float* __restrict__ a_in,
    const float* __restrict__ Wt,
    const float* __restrict__ bu_p, const float* __restrict__ ba_p,
    float* __restrict__ pose_out, float* __restrict__ a_out) {
  constexpr int PAD = K / 2;
  constexpr int RA = (2 * (OIG - 1) + K < HIN) ? (2 * (OIG - 1) + K) : HIN;
  __shared__ float tp[RA * WIN * 20];   // [row][col][20] (16 used + pad)
  __shared__ float ta[RA * WIN];
  __shared__ float wt[K * K * 16];      // [tap][l*4+j]

  int t = threadIdx.x;
  int g = (NG > 1) ? (blockIdx.x % NG) : 0;
  int c = (blockIdx.x / NG) % BC;
  int b = blockIdx.x / (NG * BC);
  int oi_lo = g * OIG;
  int rlo = max(0, 2 * oi_lo - PAD);
  int rhi = min(HIN, 2 * (oi_lo + OIG - 1) - PAD + K);
  int nrows = rhi - rlo;

  for (int q = t; q < K * K * 16; q += 256) {
    int tap = q >> 4, lj = q & 15, l = lj >> 2, j = lj & 3;
    wt[tap * 16 + lj] = Wt[((size_t)tap * BC + c) * 16 + j * 4 + l];
  }
  for (int q = t; q < nrows * WIN; q += 256) {
    int row = q / WIN, col = q % WIN;
    ta[q] = a_in[((size_t)((b * HIN + rlo + row) * WIN + col)) * BC + c];
  }
  for (int q = t; q < nrows * WIN * 4; q += 256) {
    int quad = q & 3, pc = q >> 2;
    int row = pc / WIN, col = pc % WIN;
    const float4 src = *(const float4*)(pose_in +
        (((size_t)((b * HIN + rlo + row) * WIN + col)) * BC + c) * 16 + quad * 4);
    *(float4*)(tp + (row * WIN + col) * 20 + quad * 4) = src;
  }
  __syncthreads();

  for (int s = t; s < OIG * WOUT * 16; s += 256) {
    int p = s & 15, pr = s >> 4;
    int oj = pr % WOUT;
    int oi = oi_lo + pr / WOUT;
    int ip = p >> 2, l = p & 3;
    int ih0 = 2 * oi - PAD, iw0 = 2 * oj - PAD;
    float rsum = 0.f, acc = 0.f, acc2 = 0.f;
#pragma unroll
    for (int ki = 0; ki < K; ++ki) {
      int ih = ih0 + ki;
      if (ih < 0 || ih >= HIN) continue;
      int rbase = (ih - rlo) * WIN;
#pragma unroll
      for (int kj = 0; kj < K; ++kj) {
        int iw = iw0 + kj;
        if (iw < 0 || iw >= WIN) continue;
        float ak = ta[rbase + iw];
        const float4 pm = *(const float4*)(tp + (rbase + iw) * 20 + ip * 4);
        const float4 wr = *(const float4*)(wt + (ki * K + kj) * 16 + l * 4);
        float v = pm.x * wr.x + pm.y * wr.y + pm.z * wr.z + pm.w * wr.w;
        rsum += ak;
        float av = ak * v;
        acc += av;
        acc2 += av * v;
      }
    }
    float inv = 1.f / (rsum + EPS);
    float mu = acc * inv;
    float S = rsum * inv;
    float sg = acc2 * inv - mu * mu * (2.f - S);
    sg = fmaxf(sg, 0.f) + EPS;
    float hl = 0.5f * __logf(sg);
    float ls = hl;
    ls += __shfl_xor(ls, 1, 64);
    ls += __shfl_xor(ls, 2, 64);
    ls += __shfl_xor(ls, 4, 64);
    ls += __shfl_xor(ls, 8, 64);

    size_t obase = ((size_t)(b * HOUT + oi) * WOUT + oj) * BC + c;
    pose_out[obase * 16 + p] = mu;
    if (p == 0) {
      float cost = rsum * (16.f * bu_p[0] + ls);
      a_out[obase] = sigmoidf(LAMBDA * (ba_p[0] - cost));
    }
  }
}

// ---------------------------------------------------------------------------
// 3) 1x1 conv caps with full 3-iter EM. COUT=16. One 256-thread block per
//    routing problem; votes/state in LDS. thread t -> (c = t/16, p = t%16).
// ---------------------------------------------------------------------------
template <int BIN>
__global__ __launch_bounds__(256) void cc_em_kernel(
    const float* __restrict__ pose_in, const float* __restrict__ a_arr,
    const float* __restrict__ Wt,
    const float* __restrict__ bu_p, const float* __restrict__ ba_p,
    float* __restrict__ pose_out, float* __restrict__ a_out) {
  constexpr int COUT = 16;
  __shared__ float pm_s[BIN * 16];
  __shared__ float ain_s[BIN];
  __shared__ float v_s[BIN][COUT * 16];
  __shared__ float rw_s[BIN][COUT];
  __shared__ float mu_s[COUT * 16];
  __shared__ float sg_s[COUT * 16];
  __shared__ float hl_s[COUT * 16];
  __shared__ float rsum_s[COUT];
  __shared__ float aout_s[COUT];
  __shared__ float lnap_s[BIN][COUT];

  int n = blockIdx.x, t = threadIdx.x;
  int c = t >> 4, p = t & 15;
  if (t < BIN * 16) pm_s[t] = pose_in[(size_t)n * BIN * 16 + t];
  if (t < BIN) ain_s[t] = a_arr[(size_t)n * BIN + t];
  __syncthreads();

  int ip = p >> 2, l = p & 3;
#pragma unroll
  for (int b = 0; b < BIN; ++b) {
    const float* wr = Wt + (b * COUT + c) * 16 + l;
    const float* pm = &pm_s[b * 16 + ip * 4];
    v_s[b][t] = pm[0] * wr[0] + pm[1] * wr[4] + pm[2] * wr[8] + pm[3] * wr[12];
  }
  if (t < BIN * COUT) rw_s[t / COUT][t % COUT] = (1.f / COUT) * ain_s[t / COUT];
  __syncthreads();

  for (int it = 0; it < 3; ++it) {
    if (t < COUT) {
      float s = 0.f;
#pragma unroll
      for (int b = 0; b < BIN; ++b) s += rw_s[b][t];
      rsum_s[t] = s;
    }
    __syncthreads();
    {
      float s = 0.f;
#pragma unroll
      for (int b = 0; b < BIN; ++b) s += rw_s[b][c] * v_s[b][t];
      float mu = s / (rsum_s[c] + EPS);
      mu_s[t] = mu;
      float s2 = 0.f;
#pragma unroll
      for (int b = 0; b < BIN; ++b) { float d = v_s[b][t] - mu; s2 += rw_s[b][c] * d * d; }
      float sg = s2 / (rsum_s[c] + EPS) + EPS;
      sg_s[t] = sg;
      hl_s[t] = 0.5f * __logf(sg);
    }
    __syncthreads();
    if (t < COUT) {
      float lsum = 0.f;
#pragma unroll
      for (int pp = 0; pp < 16; ++pp) lsum += hl_s[t * 16 + pp];
      float cost = rsum_s[t] * (16.f * bu_p[t] + lsum);
      aout_s[t] = sigmoidf(LAMBDA * (ba_p[t] - cost));
    }
    __syncthreads();
    if (it < 2) {
      if (t < BIN * COUT) {
        int b = t / COUT, cc = t % COUT;
        float s = __logf(EPS + aout_s[cc]) - 16.f * LN2PI_HALF;
#pragma unroll
        for (int pp = 0; pp < 16; ++pp) {
          float d = v_s[b][cc * 16 + pp] - mu_s[cc * 16 + pp];
          s += -d * d / (2.f * sg_s[cc * 16 + pp]) - hl_s[cc * 16 + pp];
        }
        lnap_s[b][cc] = s;
      }
      __syncthreads();
      if (t < BIN * COUT) {
        int b = t / COUT, cc = t % COUT;
        float m = -1e30f;
#pragma unroll
        for (int q = 0; q < COUT; ++q) m = fmaxf(m, lnap_s[b][q]);
        float Z = 0.f;
#pragma unroll
        for (int q = 0; q < COUT; ++q) Z += __expf(lnap_s[b][q] - m);
        rw_s[b][cc] = (__expf(lnap_s[b][cc] - m) / Z) * ain_s[b];
      }
      __syncthreads();
    }
  }
  pose_out[(size_t)n * COUT * 16 + t] = mu_s[t];
  if (t < COUT) a_out[(size_t)n * COUT + t] = aout_s[t];
}

// ---------------------------------------------------------------------------
// 4a) class caps M-step: one 256-thread block per (image b, capsule c).
// ---------------------------------------------------------------------------
__global__ __launch_bounds__(256) void cls_m_kernel(
    const float* __restrict__ pose5, const float* __restrict__ a5,
    const float* __restrict__ X, const float* __restrict__ W,
    const float* __restrict__ bu_p, const float* __restrict__ ba_p,
    float* __restrict__ mu_g, float* __restrict__ inv2_g,
    float* __restrict__ base_g, float* __restrict__ out,
    int first, int last) {
  int blk = blockIdx.x;                 // b*10 + c
  int c = blk % 10, b = blk / 10;
  int t = threadIdx.x;
  int lane = t & 63, wv = t >> 6;
  const float* pg = pose5 + (size_t)b * 16384;
  __shared__ float w_s[16][16];         // [jj][d]
  {
    int d = t & 15, jj = t >> 4;
    w_s[jj][d] = W[(d * 10 + c) * 16 + jj];
  }
  __syncthreads();
  const int d = t & 15;
  float wf[16];
#pragma unroll
  for (int jj = 0; jj < 16; ++jj) wf[jj] = w_s[jj][d];

  float sA = 0.f, sV[16], sV2[16];
#pragma unroll
  for (int p = 0; p < 16; ++p) { sV[p] = 0.f; sV2[p] = 0.f; }
#pragma unroll
  for (int rep = 0; rep < 4; ++rep) {
    int bi = rep * 256 + t;
    int pos = bi >> 4;
    float rw = first ? 0.1f * a5[(size_t)b * 1024 + bi]
                     : X[(size_t)blk * 1024 + bi];
    float ci = (float)(pos >> 3) * 0.125f;
    float cj = (float)(pos & 7) * 0.125f;
    const float* pp = pg + pos * 256 + d * 16;
    float pmr[16];
#pragma unroll
    for (int q = 0; q < 16; ++q) pmr[q] = pp[q];
    sA += rw;
#pragma unroll
    for (int p = 0; p < 16; ++p) {
      int ip = p >> 2, l = p & 3;
      float v = pmr[ip * 4 + 0] * wf[0 * 4 + l] + pmr[ip * 4 + 1] * wf[1 * 4 + l]
              + pmr[ip * 4 + 2] * wf[2 * 4 + l] + pmr[ip * 4 + 3] * wf[3 * 4 + l];
      if (p == 0) v += ci;
      else if (p == 1) v += cj;
      float rv = rw * v;
      sV[p] += rv;
      sV2[p] += rv * v;
    }
  }
#pragma unroll
  for (int off = 1; off < 64; off <<= 1) {
    sA += __shfl_xor(sA, off, 64);
#pragma unroll
    for (int p = 0; p < 16; ++p) {
      sV[p]  += __shfl_xor(sV[p],  off, 64);
      sV2[p] += __shfl_xor(sV2[p], off, 64);
    }
  }
  __shared__ float red[4][36];
  if (lane == 0) {
    red[wv][0] = sA;
#pragma unroll
    for (int p = 0; p < 16; ++p) { red[wv][1 + p] = sV[p]; red[wv][17 + p] = sV2[p]; }
  }
  __syncthreads();
  if (t < 16) {
    int p = t;
    float sAf  = red[0][0] + red[1][0] + red[2][0] + red[3][0];
    float sVf  = red[0][1+p] + red[1][1+p] + red[2][1+p] + red[3][1+p];
    float sV2f = red[0][17+p] + red[1][17+p] + red[2][17+p] + red[3][17+p];
    float inv = 1.f / (sAf + EPS);
    float S = sAf * inv;
    float mu = sVf * inv;
    float sg = sV2f * inv - mu * mu * (2.f - S) + EPS;
    sg = fmaxf(sg, EPS);
    mu_g[blk * 16 + p] = mu;
    inv2_g[blk * 16 + p] = 0.5f / sg;
    float hl = 0.5f * __logf(sg);
    float lsum = hl;
    lsum += __shfl_xor(lsum, 1, 64);
    lsum += __shfl_xor(lsum, 2, 64);
    lsum += __shfl_xor(lsum, 4, 64);
    lsum += __shfl_xor(lsum, 8, 64);
    if (p == 0) {
      float cost = sAf * (16.f * bu_p[c] + lsum);
      float ao = sigmoidf(LAMBDA * (ba_p[c] - cost));
      base_g[blk] = __logf(EPS + ao) - lsum - 16.f * LN2PI_HALF;
      if (last) out[blk] = ao;
    }
  }
}

// ---------------------------------------------------------------------------
// 4b) class caps E-step: 2 blocks of 512 per image; thread = one b_in.
// ---------------------------------------------------------------------------
__global__ __launch_bounds__(512) void cls_e_kernel(
    const float* __restrict__ pose5, const float* __restrict__ a5,
    const float* __restrict__ W,
    const float* __restrict__ mu_g, const float* __restrict__ inv2_g,
    const float* __restrict__ base_g, float* __restrict__ X) {
  int b = blockIdx.x >> 1;
  int t = threadIdx.x;
  int bi = ((blockIdx.x & 1) << 9) + t;
  const float* pg = pose5 + (size_t)b * 16384;
  __shared__ float w2[10][16][16];      // [c][jj][d]
  __shared__ float mu_s[160];
  __shared__ float inv2_s[160];
  __shared__ float base_s[10];
  for (int q = t; q < 2560; q += 512) {
    int dd = q & 15, jj = (q >> 4) & 15, c = q >> 8;
    w2[c][jj][dd] = W[(dd * 10 + c) * 16 + jj];
  }
  if (t < 160) { mu_s[t] = mu_g[b * 160 + t]; inv2_s[t] = inv2_g[b * 160 + t]; }
  if (t >= 160 && t < 170) base_s[t - 160] = base_g[b * 10 + (t - 160)];
  __syncthreads();

  int pos = bi >> 4, d2 = bi & 15;
  float ci = (float)(pos >> 3) * 0.125f;
  float cj = (float)(pos & 7) * 0.125f;
  const float* pp = pg + pos * 256 + d2 * 16;
  float pmr[16];
#pragma unroll
  for (int q = 0; q < 16; ++q) pmr[q] = pp[q];
  float lnap[10];
#pragma unroll
  for (int c = 0; c < 10; ++c) {
    float wf[16];
#pragma unroll
    for (int jj = 0; jj < 16; ++jj) wf[jj] = w2[c][jj][d2];
    float s = base_s[c];
#pragma unroll
    for (int p = 0; p < 16; ++p) {
      int ip = p >> 2, l = p & 3;
      float v = pmr[ip * 4 + 0] * wf[0 * 4 + l] + pmr[ip * 4 + 1] * wf[1 * 4 + l]
              + pmr[ip * 4 + 2] * wf[2 * 4 + l] + pmr[ip * 4 + 3] * wf[3 * 4 + l];
      if (p == 0) v += ci;
      else if (p == 1) v += cj;
      float dd = v - mu_s[c * 16 + p];
      s -= dd * dd * inv2_s[c * 16 + p];
    }
    lnap[c] = s;
  }
  float m = -1e30f;
#pragma unroll
  for (int c = 0; c < 10; ++c) m = fmaxf(m, lnap[c]);
  float Z = 0.f;
  float ex[10];
#pragma unroll
  for (int c = 0; c < 10; ++c) { ex[c] = __expf(lnap[c] - m); Z += ex[c]; }
  float invZ = a5[(size_t)b * 1024 + bi] / Z;
#pragma unroll
  for (int c = 0; c < 10; ++c) X[((size_t)(b * 10 + c)) * 1024 + bi] = ex[c] * invZ;
}

// ---------------------------------------------------------------------------
extern "C" void kernel_launch(void* const* d_in, const int* in_sizes, int n_in,
                              void* d_out, int out_size, void* d_ws, size_t ws_size,
                              hipStream_t stream) {
  const float* x       = (const float*)d_in[0];
  const float* conv1_w = (const float*)d_in[1];
  const float* conv1_b = (const float*)d_in[2];
  const float* pp_w    = (const float*)d_in[3];
  const float* pp_b    = (const float*)d_in[4];
  const float* pa_w    = (const float*)d_in[5];
  const float* pa_b    = (const float*)d_in[6];
  const float* dw1_w   = (const float*)d_in[7];
  const float* dw1_bu  = (const float*)d_in[8];
  const float* dw1_ba  = (const float*)d_in[9];
  const float* cc1_w   = (const float*)d_in[10];
  const float* cc1_bu  = (const float*)d_in[11];
  const float* cc1_ba  = (const float*)d_in[12];
  const float* dw2_w   = (const float*)d_in[13];
  const float* dw2_bu  = (const float*)d_in[14];
  const float* dw2_ba  = (const float*)d_in[15];
  const float* cc2_w   = (const float*)d_in[16];
  const float* cc2_bu  = (const float*)d_in[17];
  const float* cc2_ba  = (const float*)d_in[18];
  const float* cls_w   = (const float*)d_in[19];
  const float* cls_bu  = (const float*)d_in[20];
  const float* cls_ba  = (const float*)d_in[21];
  float* out = (float*)d_out;

  float* ws = (float*)d_ws;
  float* pose1 = ws;                  // 32*30*30*128
  float* a1    = ws + 3686400;        // 32*30*30*8
  float* pose2 = ws + 3916800;        // 32*15*15*128
  float* a2    = ws + 4838400;        // 32*15*15*8
  float* pose3 = ws;                  // 32*15*15*256 (aliases dead pose1)
  float* a3    = ws + 1843200;        // 32*15*15*16
  float* pose4 = ws + 1958400;        // 32*8*8*256
  float* a4    = ws + 2482688;        // 32*8*8*16
  float* pose5 = ws + 2515456;        // 32*8*8*256
  float* a5    = ws + 3039744;        // 32*8*8*16
  float* Xbuf  = ws + 3072512;        // 32*10*1024
  float* mu_g  = ws + 3400192;        // 32*160
  float* inv2_g= ws + 3405312;        // 32*160
  float* base_g= ws + 3410432;        // 32*10

  stem_primary_kernel<<<2880, 256, 0, stream>>>(x, conv1_w, conv1_b,
                                                pp_w, pp_b, pa_w, pa_b, pose1, a1);
  // dw1: K=7, BC=8, 30x30 -> 15x15, 3 oi-groups of 5. grid = 32*8*3 = 768.
  dw_caps_kernel<7, 8, 30, 30, 15, 15, 5, 3><<<768, 256, 0, stream>>>(
      pose1, a1, dw1_w, dw1_bu, dw1_ba, pose2, a2);
  cc_em_kernel<8><<<7200, 256, 0, stream>>>(pose2, a2, cc1_w, cc1_bu, cc1_ba, pose3, a3);
  // dw2: K=5, BC=16, 15x15 -> 8x8, 1 oi-group of 8. grid = 32*16 = 512.
  dw_caps_kernel<5, 16, 15, 15, 8, 8, 8, 1><<<512, 256, 0, stream>>>(
      pose3, a3, dw2_w, dw2_bu, dw2_ba, pose4, a4);
  cc_em_kernel<16><<<2048, 256, 0, stream>>>(pose4, a4, cc2_w, cc2_bu, cc2_ba, pose5, a5);
  cls_m_kernel<<<320, 256, 0, stream>>>(pose5, a5, Xbuf, cls_w, cls_bu, cls_ba,
                                        mu_g, inv2_g, base_g, out, 1, 0);
  cls_e_kernel<<<64, 512, 0, stream>>>(pose5, a5, cls_w, mu_g, inv2_g, base_g, Xbuf);
  cls_m_kernel<<<320, 256, 0, stream>>>(pose5, a5, Xbuf, cls_w, cls_bu, cls_ba,
                                        mu_g, inv2_g, base_g, out, 0, 0);
  cls_e_kernel<<<64, 512, 0, stream>>>(pose5, a5, cls_w, mu_g, inv2_g, base_g, Xbuf);
  cls_m_kernel<<<320, 256, 0, stream>>>(pose5, a5, Xbuf, cls_w, cls_bu, cls_ba,
                                        mu_g, inv2_g, base_g, out, 0, 1);
}

// Round 9
// 284.575 us; speedup vs baseline: 2.8228x; 1.0059x over previous
//
#include <hip/hip_runtime.h>
#include <hip/hip_bf16.h>

#define EPS 1e-8f
#define LAMBDA 1e-3f
#define LN2PI_HALF 0.9189385332046727f

__device__ __forceinline__ float sigmoidf(float x) { return 1.f / (1.f + __expf(-x)); }

// ---------------------------------------------------------------------------
// 1) fused conv stem + primary caps, TILED. One 256-thread block per 10
//    consecutive oj at fixed (b,oi). All weights staged in LDS once per block.
// ---------------------------------------------------------------------------
__global__ __launch_bounds__(256) void stem_primary_kernel(
    const float* __restrict__ x, const float* __restrict__ w,
    const float* __restrict__ bias,
    const float* __restrict__ wp, const float* __restrict__ bp,
    const float* __restrict__ wa, const float* __restrict__ ba,
    float* __restrict__ pose, float* __restrict__ a) {
  __shared__ float wp_s[64][128];   // 32 KB
  __shared__ float wc_s[25][64];    // 6.4 KB
  __shared__ float wa_s[64][8];     // 2 KB
  __shared__ float bias_s[64];
  __shared__ float bp_s[128];
  __shared__ float ba_s[8];
  __shared__ float xs[5][23];
  __shared__ float ys[10][64];

  int t = threadIdx.x;
  int jt = blockIdx.x % 3;
  int oi = (blockIdx.x / 3) % 30;
  int b  = blockIdx.x / 90;
  int oj0 = jt * 10;

  for (int q = t; q < 8192; q += 256) ((float*)wp_s)[q] = wp[q];
  for (int q = t; q < 1600; q += 256) ((float*)wc_s)[q] = w[q];
  for (int q = t; q < 512;  q += 256) ((float*)wa_s)[q] = wa[q];
  if (t < 64) bias_s[t] = bias[t];
  if (t < 128) bp_s[t] = bp[t];
  if (t < 8) ba_s[t] = ba[t];
  for (int q = t; q < 115; q += 256) {
    int ki = q / 23, kj = q % 23;
    xs[ki][kj] = x[(b * 64 + 2 * oi + ki) * 64 + 2 * oj0 + kj];
  }
  __syncthreads();

#pragma unroll
  for (int rep = 0; rep < 3; ++rep) {
    int q = rep * 256 + t;
    if (q < 640) {
      int pos = q >> 6, ch = q & 63;
      float s = bias_s[ch];
#pragma unroll
      for (int ki = 0; ki < 5; ++ki)
#pragma unroll
        for (int kj = 0; kj < 5; ++kj)
          s += xs[ki][2 * pos + kj] * wc_s[ki * 5 + kj][ch];
      ys[pos][ch] = fmaxf(s, 0.f);
    }
  }
  __syncthreads();

  int w_ = t >> 7, d = t & 127;
  float acc[5];
#pragma unroll
  for (int j = 0; j < 5; ++j) acc[j] = bp_s[d];
  for (int c = 0; c < 64; ++c) {
    float wv = wp_s[c][d];
#pragma unroll
    for (int j = 0; j < 5; ++j) acc[j] += ys[w_ + 2 * j][c] * wv;
  }
  size_t rowbase = (size_t)(b * 30 + oi) * 30 + oj0;
#pragma unroll
  for (int j = 0; j < 5; ++j)
    pose[(rowbase + w_ + 2 * j) * 128 + d] = acc[j];

  if (t < 80) {
    int pos = t >> 3, jj = t & 7;
    float s = ba_s[jj];
#pragma unroll 8
    for (int c = 0; c < 64; ++c) s += ys[pos][c] * wa_s[c][jj];
    a[(rowbase + pos) * 8 + jj] = sigmoidf(s);
  }
}

// ---------------------------------------------------------------------------
// 2) depthwise caps v3 — LDS-TILED. Block = (b, capsule c, oi-group g).
// ---------------------------------------------------------------------------
template <int K, int BC, int HIN, int WIN, int HOUT, int WOUT, int OIG, int NG>
__global__ __launch_bounds__(256) void dw_caps_kernel(
    const float* __restrict__ pose_in, const float* __restrict__ a_in,
    const float* __restrict__ Wt,
    const float* __restrict__ bu_p, const float* __restrict__ ba_p,
    float* __restrict__ pose_out, float* __restrict__ a_out) {
  constexpr int PAD = K / 2;
  constexpr int RA = (2 * (OIG - 1) + K < HIN) ? (2 * (OIG - 1) + K) : HIN;
  __shared__ float tp[RA * WIN * 20];
  __shared__ float ta[RA * WIN];
  __shared__ float wt[K * K * 16];

  int t = threadIdx.x;
  int g = (NG > 1) ? (blockIdx.x % NG) : 0;
  int c = (blockIdx.x / NG) % BC;
  int b = blockIdx.x / (NG * BC);
  int oi_lo = g * OIG;
  int rlo = max(0, 2 * oi_lo - PAD);
  int rhi = min(HIN, 2 * (oi_lo + OIG - 1) - PAD + K);
  int nrows = rhi - rlo;

  for (int q = t; q < K * K * 16; q += 256) {
    int tap = q >> 4, lj = q & 15, l = lj >> 2, j = lj & 3;
    wt[tap * 16 + lj] = Wt[((size_t)tap * BC + c) * 16 + j * 4 + l];
  }
  for (int q = t; q < nrows * WIN; q += 256) {
    int row = q / WIN, col = q % WIN;
    ta[q] = a_in[((size_t)((b * HIN + rlo + row) * WIN + col)) * BC + c];
  }
  for (int q = t; q < nrows * WIN * 4; q += 256) {
    int quad = q & 3, pc = q >> 2;
    int row = pc / WIN, col = pc % WIN;
    const float4 src = *(const float4*)(pose_in +
        (((size_t)((b * HIN + rlo + row) * WIN + col)) * BC + c) * 16 + quad * 4);
    *(float4*)(tp + (row * WIN + col) * 20 + quad * 4) = src;
  }
  __syncthreads();

  for (int s = t; s < OIG * WOUT * 16; s += 256) {
    int p = s & 15, pr = s >> 4;
    int oj = pr % WOUT;
    int oi = oi_lo + pr / WOUT;
    int ip = p >> 2, l = p & 3;
    int ih0 = 2 * oi - PAD, iw0 = 2 * oj - PAD;
    float rsum = 0.f, acc = 0.f, acc2 = 0.f;
#pragma unroll
    for (int ki = 0; ki < K; ++ki) {
      int ih = ih0 + ki;
      if (ih < 0 || ih >= HIN) continue;
      int rbase = (ih - rlo) * WIN;
#pragma unroll
      for (int kj = 0; kj < K; ++kj) {
        int iw = iw0 + kj;
        if (iw < 0 || iw >= WIN) continue;
        float ak = ta[rbase + iw];
        const float4 pm = *(const float4*)(tp + (rbase + iw) * 20 + ip * 4);
        const float4 wr = *(const float4*)(wt + (ki * K + kj) * 16 + l * 4);
        float v = pm.x * wr.x + pm.y * wr.y + pm.z * wr.z + pm.w * wr.w;
        rsum += ak;
        float av = ak * v;
        acc += av;
        acc2 += av * v;
      }
    }
    float inv = 1.f / (rsum + EPS);
    float mu = acc * inv;
    float S = rsum * inv;
    float sg = acc2 * inv - mu * mu * (2.f - S);
    sg = fmaxf(sg, 0.f) + EPS;
    float hl = 0.5f * __logf(sg);
    float ls = hl;
    ls += __shfl_xor(ls, 1, 64);
    ls += __shfl_xor(ls, 2, 64);
    ls += __shfl_xor(ls, 4, 64);
    ls += __shfl_xor(ls, 8, 64);

    size_t obase = ((size_t)(b * HOUT + oi) * WOUT + oj) * BC + c;
    pose_out[obase * 16 + p] = mu;
    if (p == 0) {
      float cost = rsum * (16.f * bu_p[0] + ls);
      a_out[obase] = sigmoidf(LAMBDA * (ba_p[0] - cost));
    }
  }
}

// ---------------------------------------------------------------------------
// 3) 1x1 conv caps EM v2 — votes + EM state IN REGISTERS. Thread (c,p) owns
//    v[b] for its (c,p) column, and its own mu/inv2/hl. M-step: broadcast
//    rw reads + register FMAs. E-step: own-register partials + width-16
//    butterfly; lnap_s stride-17 (conflict-free). Was: v_s/mu_s/sg_s LDS
//    reads with 2-bank pattern -> 5.7M conflict cycles/dispatch, 51 us.
// ---------------------------------------------------------------------------
template <int BIN>
__global__ __launch_bounds__(256) void cc_em_kernel(
    const float* __restrict__ pose_in, const float* __restrict__ a_arr,
    const float* __restrict__ Wt,
    const float* __restrict__ bu_p, const float* __restrict__ ba_p,
    float* __restrict__ pose_out, float* __restrict__ a_out) {
  constexpr int COUT = 16;
  __shared__ float w_s[BIN * COUT * 16];
  __shared__ float pm_s[BIN * 16];
  __shared__ float ain_s[BIN];
  __shared__ float rw_s[BIN][COUT];
  __shared__ float lnap_s[BIN][17];

  int n = blockIdx.x, t = threadIdx.x;
  int c = t >> 4, p = t & 15;
  int ip = p >> 2, l = p & 3;

  for (int q = t; q < BIN * COUT * 16; q += 256) w_s[q] = Wt[q];
  if (t < BIN * 16) pm_s[t] = pose_in[(size_t)n * BIN * 16 + t];
  if (t < BIN) ain_s[t] = a_arr[(size_t)n * BIN + t];
  if (t < BIN * COUT) rw_s[t >> 4][t & 15] = (1.f / COUT) * a_arr[(size_t)n * BIN + (t >> 4)];
  float bu = bu_p[c], ba = ba_p[c];
  __syncthreads();

  float v[BIN];
#pragma unroll
  for (int b = 0; b < BIN; ++b) {
    const float* wr = w_s + (b * COUT + c) * 16 + l;
    const float* pm = pm_s + b * 16 + ip * 4;
    v[b] = pm[0] * wr[0] + pm[1] * wr[4] + pm[2] * wr[8] + pm[3] * wr[12];
  }

  float mu = 0.f, ao = 0.f;
  for (int it = 0; it < 3; ++it) {
    float sA = 0.f, sV = 0.f, sV2 = 0.f;
#pragma unroll
    for (int b = 0; b < BIN; ++b) {
      float rw = rw_s[b][c];
      sA += rw;
      float rv = rw * v[b];
      sV += rv;
      sV2 += rv * v[b];
    }
    float inv = 1.f / (sA + EPS);
    mu = sV * inv;
    float S = sA * inv;
    float sg = sV2 * inv - mu * mu * (2.f - S) + EPS;
    sg = fmaxf(sg, EPS);
    float hl = 0.5f * __logf(sg);
    float inv2 = 0.5f / sg;
    float hlsum = hl;
    hlsum += __shfl_xor(hlsum, 1, 16);
    hlsum += __shfl_xor(hlsum, 2, 16);
    hlsum += __shfl_xor(hlsum, 4, 16);
    hlsum += __shfl_xor(hlsum, 8, 16);
    float cost = sA * (16.f * bu + hlsum);
    ao = sigmoidf(LAMBDA * (ba - cost));
    if (it < 2) {
      float red[BIN];
#pragma unroll
      for (int b = 0; b < BIN; ++b) { float d = v[b] - mu; red[b] = d * d * inv2; }
#pragma unroll
      for (int m = 1; m < 16; m <<= 1)
#pragma unroll
        for (int b = 0; b < BIN; ++b) red[b] += __shfl_xor(red[b], m, 16);
      if (p < BIN)
        lnap_s[p][c] = __logf(EPS + ao) - hlsum - 16.f * LN2PI_HALF - red[p];
      __syncthreads();
      if (t < BIN * COUT) {
        int b = t >> 4, cc = t & 15;
        float mx = -1e30f;
#pragma unroll
        for (int q = 0; q < COUT; ++q) mx = fmaxf(mx, lnap_s[b][q]);
        float Z = 0.f;
#pragma unroll
        for (int q = 0; q < COUT; ++q) Z += __expf(lnap_s[b][q] - mx);
        rw_s[b][cc] = (__expf(lnap_s[b][cc] - mx) / Z) * ain_s[b];
      }
      __syncthreads();
    }
  }
  pose_out[(size_t)n * COUT * 16 + t] = mu;
  if (p == 0) a_out[(size_t)n * COUT + c] = ao;
}

// ---------------------------------------------------------------------------
// 4a) class caps M-step: one 256-thread block per (image b, capsule c).
// ---------------------------------------------------------------------------
__global__ __launch_bounds__(256) void cls_m_kernel(
    const float* __restrict__ pose5, const float* __restrict__ a5,
    const float* __restrict__ X, const float* __restrict__ W,
    const float* __restrict__ bu_p, const float* __restrict__ ba_p,
    float* __restrict__ mu_g, float* __restrict__ inv2_g,
    float* __restrict__ base_g, float* __restrict__ out,
    int first, int last) {
  int blk = blockIdx.x;                 // b*10 + c
  int c = blk % 10, b = blk / 10;
  int t = threadIdx.x;
  int lane = t & 63, wv = t >> 6;
  const float* pg = pose5 + (size_t)b * 16384;
  __shared__ float w_s[16][16];         // [jj][d]
  {
    int d = t & 15, jj = t >> 4;
    w_s[jj][d] = W[(d * 10 + c) * 16 + jj];
  }
  __syncthreads();
  const int d = t & 15;
  float wf[16];
#pragma unroll
  for (int jj = 0; jj < 16; ++jj) wf[jj] = w_s[jj][d];

  float sA = 0.f, sV[16], sV2[16];
#pragma unroll
  for (int p = 0; p < 16; ++p) { sV[p] = 0.f; sV2[p] = 0.f; }
#pragma unroll
  for (int rep = 0; rep < 4; ++rep) {
    int bi = rep * 256 + t;
    int pos = bi >> 4;
    float rw = first ? 0.1f * a5[(size_t)b * 1024 + bi]
                     : X[(size_t)blk * 1024 + bi];
    float ci = (float)(pos >> 3) * 0.125f;
    float cj = (float)(pos & 7) * 0.125f;
    const float* pp = pg + pos * 256 + d * 16;
    float pmr[16];
#pragma unroll
    for (int q = 0; q < 16; ++q) pmr[q] = pp[q];
    sA += rw;
#pragma unroll
    for (int p = 0; p < 16; ++p) {
      int ip = p >> 2, l = p & 3;
      float v = pmr[ip * 4 + 0] * wf[0 * 4 + l] + pmr[ip * 4 + 1] * wf[1 * 4 + l]
              + pmr[ip * 4 + 2] * wf[2 * 4 + l] + pmr[ip * 4 + 3] * wf[3 * 4 + l];
      if (p == 0) v += ci;
      else if (p == 1) v += cj;
      float rv = rw * v;
      sV[p] += rv;
      sV2[p] += rv * v;
    }
  }
#pragma unroll
  for (int off = 1; off < 64; off <<= 1) {
    sA += __shfl_xor(sA, off, 64);
#pragma unroll
    for (int p = 0; p < 16; ++p) {
      sV[p]  += __shfl_xor(sV[p],  off, 64);
      sV2[p] += __shfl_xor(sV2[p], off, 64);
    }
  }
  __shared__ float red[4][36];
  if (lane == 0) {
    red[wv][0] = sA;
#pragma unroll
    for (int p = 0; p < 16; ++p) { red[wv][1 + p] = sV[p]; red[wv][17 + p] = sV2[p]; }
  }
  __syncthreads();
  if (t < 16) {
    int p = t;
    float sAf  = red[0][0] + red[1][0] + red[2][0] + red[3][0];
    float sVf  = red[0][1+p] + red[1][1+p] + red[2][1+p] + red[3][1+p];
    float sV2f = red[0][17+p] + red[1][17+p] + red[2][17+p] + red[3][17+p];
    float inv = 1.f / (sAf + EPS);
    float S = sAf * inv;
    float mu = sVf * inv;
    float sg = sV2f * inv - mu * mu * (2.f - S) + EPS;
    sg = fmaxf(sg, EPS);
    mu_g[blk * 16 + p] = mu;
    inv2_g[blk * 16 + p] = 0.5f / sg;
    float hl = 0.5f * __logf(sg);
    float lsum = hl;
    lsum += __shfl_xor(lsum, 1, 64);
    lsum += __shfl_xor(lsum, 2, 64);
    lsum += __shfl_xor(lsum, 4, 64);
    lsum += __shfl_xor(lsum, 8, 64);
    if (p == 0) {
      float cost = sAf * (16.f * bu_p[c] + lsum);
      float ao = sigmoidf(LAMBDA * (ba_p[c] - cost));
      base_g[blk] = __logf(EPS + ao) - lsum - 16.f * LN2PI_HALF;
      if (last) out[blk] = ao;
    }
  }
}

// ---------------------------------------------------------------------------
// 4b) class caps E-step: 2 blocks of 512 per image; thread = one b_in.
// ---------------------------------------------------------------------------
__global__ __launch_bounds__(512) void cls_e_kernel(
    const float* __restrict__ pose5, const float* __restrict__ a5,
    const float* __restrict__ W,
    const float* __restrict__ mu_g, const float* __restrict__ inv2_g,
    const float* __restrict__ base_g, float* __restrict__ X) {
  int b = blockIdx.x >> 1;
  int t = threadIdx.x;
  int bi = ((blockIdx.x & 1) << 9) + t;
  const float* pg = pose5 + (size_t)b * 16384;
  __shared__ float w2[10][16][16];      // [c][jj][d]
  __shared__ float mu_s[160];
  __shared__ float inv2_s[160];
  __shared__ float base_s[10];
  for (int q = t; q < 2560; q += 512) {
    int dd = q & 15, jj = (q >> 4) & 15, c = q >> 8;
    w2[c][jj][dd] = W[(dd * 10 + c) * 16 + jj];
  }
  if (t < 160) { mu_s[t] = mu_g[b * 160 + t]; inv2_s[t] = inv2_g[b * 160 + t]; }
  if (t >= 160 && t < 170) base_s[t - 160] = base_g[b * 10 + (t - 160)];
  __syncthreads();

  int pos = bi >> 4, d2 = bi & 15;
  float ci = (float)(pos >> 3) * 0.125f;
  float cj = (float)(pos & 7) * 0.125f;
  const float* pp = pg + pos * 256 + d2 * 16;
  float pmr[16];
#pragma unroll
  for (int q = 0; q < 16; ++q) pmr[q] = pp[q];
  float lnap[10];
#pragma unroll
  for (int c = 0; c < 10; ++c) {
    float wf[16];
#pragma unroll
    for (int jj = 0; jj < 16; ++jj) wf[jj] = w2[c][jj][d2];
    float s = base_s[c];
#pragma unroll
    for (int p = 0; p < 16; ++p) {
      int ip = p >> 2, l = p & 3;
      float v = pmr[ip * 4 + 0] * wf[0 * 4 + l] + pmr[ip * 4 + 1] * wf[1 * 4 + l]
              + pmr[ip * 4 + 2] * wf[2 * 4 + l] + pmr[ip * 4 + 3] * wf[3 * 4 + l];
      if (p == 0) v += ci;
      else if (p == 1) v += cj;
      float dd = v - mu_s[c * 16 + p];
      s -= dd * dd * inv2_s[c * 16 + p];
    }
    lnap[c] = s;
  }
  float m = -1e30f;
#pragma unroll
  for (int c = 0; c < 10; ++c) m = fmaxf(m, lnap[c]);
  float Z = 0.f;
  float ex[10];
#pragma unroll
  for (int c = 0; c < 10; ++c) { ex[c] = __expf(lnap[c] - m); Z += ex[c]; }
  float invZ = a5[(size_t)b * 1024 + bi] / Z;
#pragma unroll
  for (int c = 0; c < 10; ++c) X[((size_t)(b * 10 + c)) * 1024 + bi] = ex[c] * invZ;
}

// ---------------------------------------------------------------------------
extern "C" void kernel_launch(void* const* d_in, const int* in_sizes, int n_in,
                              void* d_out, int out_size, void* d_ws, size_t ws_size,
                              hipStream_t stream) {
  const float* x       = (const float*)d_in[0];
  const float* conv1_w = (const float*)d_in[1];
  const float* conv1_b = (const float*)d_in[2];
  const float* pp_w    = (const float*)d_in[3];
  const float* pp_b    = (const float*)d_in[4];
  const float* pa_w    = (const float*)d_in[5];
  const float* pa_b    = (const float*)d_in[6];
  const float* dw1_w   = (const float*)d_in[7];
  const float* dw1_bu  = (const float*)d_in[8];
  const float* dw1_ba  = (const float*)d_in[9];
  const float* cc1_w   = (const float*)d_in[10];
  const float* cc1_bu  = (const float*)d_in[11];
  const float* cc1_ba  = (const float*)d_in[12];
  const float* dw2_w   = (const float*)d_in[13];
  const float* dw2_bu  = (const float*)d_in[14];
  const float* dw2_ba  = (const float*)d_in[15];
  const float* cc2_w   = (const float*)d_in[16];
  const float* cc2_bu  = (const float*)d_in[17];
  const float* cc2_ba  = (const float*)d_in[18];
  const float* cls_w   = (const float*)d_in[19];
  const float* cls_bu  = (const float*)d_in[20];
  const float* cls_ba  = (const float*)d_in[21];
  float* out = (float*)d_out;

  float* ws = (float*)d_ws;
  float* pose1 = ws;                  // 32*30*30*128
  float* a1    = ws + 3686400;        // 32*30*30*8
  float* pose2 = ws + 3916800;        // 32*15*15*128
  float* a2    = ws + 4838400;        // 32*15*15*8
  float* pose3 = ws;                  // 32*15*15*256 (aliases dead pose1)
  float* a3    = ws + 1843200;        // 32*15*15*16
  float* pose4 = ws + 1958400;        // 32*8*8*256
  float* a4    = ws + 2482688;        // 32*8*8*16
  float* pose5 = ws + 2515456;        // 32*8*8*256
  float* a5    = ws + 3039744;        // 32*8*8*16
  float* Xbuf  = ws + 3072512;        // 32*10*1024
  float* mu_g  = ws + 3400192;        // 32*160
  float* inv2_g= ws + 3405312;        // 32*160
  float* base_g= ws + 3410432;        // 32*10

  stem_primary_kernel<<<2880, 256, 0, stream>>>(x, conv1_w, conv1_b,
                                                pp_w, pp_b, pa_w, pa_b, pose1, a1);
  dw_caps_kernel<7, 8, 30, 30, 15, 15, 5, 3><<<768, 256, 0, stream>>>(
      pose1, a1, dw1_w, dw1_bu, dw1_ba, pose2, a2);
  cc_em_kernel<8><<<7200, 256, 0, stream>>>(pose2, a2, cc1_w, cc1_bu, cc1_ba, pose3, a3);
  dw_caps_kernel<5, 16, 15, 15, 8, 8, 8, 1><<<512, 256, 0, stream>>>(
      pose3, a3, dw2_w, dw2_bu, dw2_ba, pose4, a4);
  cc_em_kernel<16><<<2048, 256, 0, stream>>>(pose4, a4, cc2_w, cc2_bu, cc2_ba, pose5, a5);
  cls_m_kernel<<<320, 256, 0, stream>>>(pose5, a5, Xbuf, cls_w, cls_bu, cls_ba,
                                        mu_g, inv2_g, base_g, out, 1, 0);
  cls_e_kernel<<<64, 512, 0, stream>>>(pose5, a5, cls_w, mu_g, inv2_g, base_g, Xbuf);
  cls_m_kernel<<<320, 256, 0, stream>>>(pose5, a5, Xbuf, cls_w, cls_bu, cls_ba,
                                        mu_g, inv2_g, base_g, out, 0, 0);
  cls_e_kernel<<<64, 512, 0, stream>>>(pose5, a5, cls_w, mu_g, inv2_g, base_g, Xbuf);
  cls_m_kernel<<<320, 256, 0, stream>>>(pose5, a5, Xbuf, cls_w, cls_bu, cls_ba,
                                        mu_g, inv2_g, base_g, out, 0, 1);
}

// Round 10
// 266.613 us; speedup vs baseline: 3.0130x; 1.0674x over previous
//
#include <hip/hip_runtime.h>
#include <hip/hip_bf16.h>

#define EPS 1e-8f
#define LAMBDA 1e-3f
#define LN2PI_HALF 0.9189385332046727f

__device__ __forceinline__ float sigmoidf(float x) { return 1.f / (1.f + __expf(-x)); }

// ---------------------------------------------------------------------------
// 1) fused conv stem + primary caps, TILED. One 256-thread block per 10
//    consecutive oj at fixed (b,oi). All weights staged in LDS once per block.
// ---------------------------------------------------------------------------
__global__ __launch_bounds__(256) void stem_primary_kernel(
    const float* __restrict__ x, const float* __restrict__ w,
    const float* __restrict__ bias,
    const float* __restrict__ wp, const float* __restrict__ bp,
    const float* __restrict__ wa, const float* __restrict__ ba,
    float* __restrict__ pose, float* __restrict__ a) {
  __shared__ float wp_s[64][128];   // 32 KB
  __shared__ float wc_s[25][64];    // 6.4 KB
  __shared__ float wa_s[64][8];     // 2 KB
  __shared__ float bias_s[64];
  __shared__ float bp_s[128];
  __shared__ float ba_s[8];
  __shared__ float xs[5][23];
  __shared__ float ys[10][64];

  int t = threadIdx.x;
  int jt = blockIdx.x % 3;
  int oi = (blockIdx.x / 3) % 30;
  int b  = blockIdx.x / 90;
  int oj0 = jt * 10;

  for (int q = t; q < 8192; q += 256) ((float*)wp_s)[q] = wp[q];
  for (int q = t; q < 1600; q += 256) ((float*)wc_s)[q] = w[q];
  for (int q = t; q < 512;  q += 256) ((float*)wa_s)[q] = wa[q];
  if (t < 64) bias_s[t] = bias[t];
  if (t < 128) bp_s[t] = bp[t];
  if (t < 8) ba_s[t] = ba[t];
  for (int q = t; q < 115; q += 256) {
    int ki = q / 23, kj = q % 23;
    xs[ki][kj] = x[(b * 64 + 2 * oi + ki) * 64 + 2 * oj0 + kj];
  }
  __syncthreads();

#pragma unroll
  for (int rep = 0; rep < 3; ++rep) {
    int q = rep * 256 + t;
    if (q < 640) {
      int pos = q >> 6, ch = q & 63;
      float s = bias_s[ch];
#pragma unroll
      for (int ki = 0; ki < 5; ++ki)
#pragma unroll
        for (int kj = 0; kj < 5; ++kj)
          s += xs[ki][2 * pos + kj] * wc_s[ki * 5 + kj][ch];
      ys[pos][ch] = fmaxf(s, 0.f);
    }
  }
  __syncthreads();

  int w_ = t >> 7, d = t & 127;
  float acc[5];
#pragma unroll
  for (int j = 0; j < 5; ++j) acc[j] = bp_s[d];
  for (int c = 0; c < 64; ++c) {
    float wv = wp_s[c][d];
#pragma unroll
    for (int j = 0; j < 5; ++j) acc[j] += ys[w_ + 2 * j][c] * wv;
  }
  size_t rowbase = (size_t)(b * 30 + oi) * 30 + oj0;
#pragma unroll
  for (int j = 0; j < 5; ++j)
    pose[(rowbase + w_ + 2 * j) * 128 + d] = acc[j];

  if (t < 80) {
    int pos = t >> 3, jj = t & 7;
    float s = ba_s[jj];
#pragma unroll 8
    for (int c = 0; c < 64; ++c) s += ys[pos][c] * wa_s[c][jj];
    a[(rowbase + pos) * 8 + jj] = sigmoidf(s);
  }
}

// ---------------------------------------------------------------------------
// 2) depthwise caps v3 — LDS-TILED. Block = (b, capsule c, oi-group g).
// ---------------------------------------------------------------------------
template <int K, int BC, int HIN, int WIN, int HOUT, int WOUT, int OIG, int NG>
__global__ __launch_bounds__(256) void dw_caps_kernel(
    const float* __restrict__ pose_in, const float* __restrict__ a_in,
    const float* __restrict__ Wt,
    const float* __restrict__ bu_p, const float* __restrict__ ba_p,
    float* __restrict__ pose_out, float* __restrict__ a_out) {
  constexpr int PAD = K / 2;
  constexpr int RA = (2 * (OIG - 1) + K < HIN) ? (2 * (OIG - 1) + K) : HIN;
  __shared__ float tp[RA * WIN * 20];
  __shared__ float ta[RA * WIN];
  __shared__ float wt[K * K * 16];

  int t = threadIdx.x;
  int g = (NG > 1) ? (blockIdx.x % NG) : 0;
  int c = (blockIdx.x / NG) % BC;
  int b = blockIdx.x / (NG * BC);
  int oi_lo = g * OIG;
  int rlo = max(0, 2 * oi_lo - PAD);
  int rhi = min(HIN, 2 * (oi_lo + OIG - 1) - PAD + K);
  int nrows = rhi - rlo;

  for (int q = t; q < K * K * 16; q += 256) {
    int tap = q >> 4, lj = q & 15, l = lj >> 2, j = lj & 3;
    wt[tap * 16 + lj] = Wt[((size_t)tap * BC + c) * 16 + j * 4 + l];
  }
  for (int q = t; q < nrows * WIN; q += 256) {
    int row = q / WIN, col = q % WIN;
    ta[q] = a_in[((size_t)((b * HIN + rlo + row) * WIN + col)) * BC + c];
  }
  for (int q = t; q < nrows * WIN * 4; q += 256) {
    int quad = q & 3, pc = q >> 2;
    int row = pc / WIN, col = pc % WIN;
    const float4 src = *(const float4*)(pose_in +
        (((size_t)((b * HIN + rlo + row) * WIN + col)) * BC + c) * 16 + quad * 4);
    *(float4*)(tp + (row * WIN + col) * 20 + quad * 4) = src;
  }
  __syncthreads();

  for (int s = t; s < OIG * WOUT * 16; s += 256) {
    int p = s & 15, pr = s >> 4;
    int oj = pr % WOUT;
    int oi = oi_lo + pr / WOUT;
    int ip = p >> 2, l = p & 3;
    int ih0 = 2 * oi - PAD, iw0 = 2 * oj - PAD;
    float rsum = 0.f, acc = 0.f, acc2 = 0.f;
#pragma unroll
    for (int ki = 0; ki < K; ++ki) {
      int ih = ih0 + ki;
      if (ih < 0 || ih >= HIN) continue;
      int rbase = (ih - rlo) * WIN;
#pragma unroll
      for (int kj = 0; kj < K; ++kj) {
        int iw = iw0 + kj;
        if (iw < 0 || iw >= WIN) continue;
        float ak = ta[rbase + iw];
        const float4 pm = *(const float4*)(tp + (rbase + iw) * 20 + ip * 4);
        const float4 wr = *(const float4*)(wt + (ki * K + kj) * 16 + l * 4);
        float v = pm.x * wr.x + pm.y * wr.y + pm.z * wr.z + pm.w * wr.w;
        rsum += ak;
        float av = ak * v;
        acc += av;
        acc2 += av * v;
      }
    }
    float inv = 1.f / (rsum + EPS);
    float mu = acc * inv;
    float S = rsum * inv;
    float sg = acc2 * inv - mu * mu * (2.f - S);
    sg = fmaxf(sg, 0.f) + EPS;
    float hl = 0.5f * __logf(sg);
    float ls = hl;
    ls += __shfl_xor(ls, 1, 64);
    ls += __shfl_xor(ls, 2, 64);
    ls += __shfl_xor(ls, 4, 64);
    ls += __shfl_xor(ls, 8, 64);

    size_t obase = ((size_t)(b * HOUT + oi) * WOUT + oj) * BC + c;
    pose_out[obase * 16 + p] = mu;
    if (p == 0) {
      float cost = rsum * (16.f * bu_p[0] + ls);
      a_out[obase] = sigmoidf(LAMBDA * (ba_p[0] - cost));
    }
  }
}

// ---------------------------------------------------------------------------
// 3) 1x1 conv caps EM v3 — ONE PROBLEM PER WAVE. Block = 4 problem-waves +
//    shared weight staging. Lane = (c = lane>>2, q = lane&3); lane owns
//    p = 4q+l, l=0..3: votes v[b][4], rw[b], mu/inv2 all in registers.
//    Reductions: hl/q-sums via 2 shuffles; softmax over c via 4-step
//    butterfly. ZERO __syncthreads in EM loop. (Was: 256 thr/problem,
//    ~300 inst/thread of butterfly+sync overhead -> 100x FLOP bloat, 50 us.)
// ---------------------------------------------------------------------------
template <int BIN>
__global__ __launch_bounds__(256) void cc_em_kernel(
    const float* __restrict__ pose_in, const float* __restrict__ a_arr,
    const float* __restrict__ Wt,
    const float* __restrict__ bu_p, const float* __restrict__ ba_p,
    float* __restrict__ pose_out, float* __restrict__ a_out) {
  constexpr int COUT = 16;
  // weights transposed per (b,c): wt_s[(b*16+c)*20 + l*4+k] = W[b][c][k*4+l]
  // stride 20 (80B): b128 reads at most 2-way bank-aliased (free).
  __shared__ float wt_s[BIN * COUT * 20];
  int t = threadIdx.x;
  for (int idx = t; idx < BIN * COUT * 16; idx += 256) {
    int lk = idx & 15, l = lk >> 2, k = lk & 3;
    int bc = idx >> 4;
    wt_s[bc * 20 + l * 4 + k] = Wt[bc * 16 + k * 4 + l];
  }
  __syncthreads();

  int wave = t >> 6, lane = t & 63;
  int n = blockIdx.x * 4 + wave;
  int c = lane >> 2;       // output capsule 0..15
  int q = lane & 3;        // pose-row quad; this lane owns p = 4q+l

  float ain[BIN], rw[BIN];
  float4 pmq[BIN];
#pragma unroll
  for (int b = 0; b < BIN; ++b) {
    ain[b] = a_arr[(size_t)n * BIN + b];
    rw[b] = (1.f / 16.f) * ain[b];
    pmq[b] = *(const float4*)(pose_in + (size_t)n * BIN * 16 + b * 16 + q * 4);
  }
  float bu = bu_p[c], ba = ba_p[c];

  // votes: v[b][l] = dot(pmq[b], W^T[b][c][l*4..l*4+3])
  float v[BIN][4];
#pragma unroll
  for (int b = 0; b < BIN; ++b) {
    const float* wr = wt_s + (b * 16 + c) * 20;
#pragma unroll
    for (int l = 0; l < 4; ++l) {
      const float4 w4 = *(const float4*)(wr + l * 4);
      v[b][l] = pmq[b].x * w4.x + pmq[b].y * w4.y + pmq[b].z * w4.z + pmq[b].w * w4.w;
    }
  }

  float mu[4], inv2[4], lsum = 0.f, ao = 0.f;
  for (int it = 0; it < 3; ++it) {
    // M-step (own c, own 4 p's)
    float sA = 0.f, sV[4] = {0, 0, 0, 0}, sV2[4] = {0, 0, 0, 0};
#pragma unroll
    for (int b = 0; b < BIN; ++b) {
      sA += rw[b];
#pragma unroll
      for (int l = 0; l < 4; ++l) {
        float rv = rw[b] * v[b][l];
        sV[l] += rv;
        sV2[l] += rv * v[b][l];
      }
    }
    float inv = 1.f / (sA + EPS);
    float S = sA * inv;
    lsum = 0.f;
#pragma unroll
    for (int l = 0; l < 4; ++l) {
      mu[l] = sV[l] * inv;
      float sg = sV2[l] * inv - mu[l] * mu[l] * (2.f - S) + EPS;
      sg = fmaxf(sg, EPS);
      inv2[l] = 0.5f / sg;
      lsum += 0.5f * __logf(sg);
    }
    lsum += __shfl_xor(lsum, 1, 64);   // sum over the 4 q-lanes of this c
    lsum += __shfl_xor(lsum, 2, 64);
    float cost = sA * (16.f * bu + lsum);
    ao = sigmoidf(LAMBDA * (ba - cost));

    if (it < 2) {
      // E-step: term[b] = sum_p (v-mu)^2 * inv2  (own 4 p + q-butterfly)
      float term[BIN];
#pragma unroll
      for (int b = 0; b < BIN; ++b) {
        float s = 0.f;
#pragma unroll
        for (int l = 0; l < 4; ++l) {
          float d = v[b][l] - mu[l];
          s += d * d * inv2[l];
        }
        term[b] = s;
      }
#pragma unroll
      for (int b = 0; b < BIN; ++b) {
        term[b] += __shfl_xor(term[b], 1, 64);
        term[b] += __shfl_xor(term[b], 2, 64);
      }
      float basec = __logf(EPS + ao) - lsum - 16.f * LN2PI_HALF;
      float lnap[BIN], Z[BIN];
#pragma unroll
      for (int b = 0; b < BIN; ++b) lnap[b] = basec - term[b];
      // softmax over c: lanes with same q sit at stride 4 -> xor 4,8,16,32
      float mx[BIN];
#pragma unroll
      for (int b = 0; b < BIN; ++b) mx[b] = lnap[b];
#pragma unroll
      for (int m = 4; m < 64; m <<= 1)
#pragma unroll
        for (int b = 0; b < BIN; ++b) mx[b] = fmaxf(mx[b], __shfl_xor(mx[b], m, 64));
#pragma unroll
      for (int b = 0; b < BIN; ++b) { lnap[b] = __expf(lnap[b] - mx[b]); Z[b] = lnap[b]; }
#pragma unroll
      for (int m = 4; m < 64; m <<= 1)
#pragma unroll
        for (int b = 0; b < BIN; ++b) Z[b] += __shfl_xor(Z[b], m, 64);
#pragma unroll
      for (int b = 0; b < BIN; ++b) rw[b] = lnap[b] / Z[b] * ain[b];
    }
  }
  // output: lane writes its 4 pose components contiguously
  float4 om = make_float4(mu[0], mu[1], mu[2], mu[3]);
  *(float4*)(pose_out + (size_t)n * 256 + c * 16 + q * 4) = om;
  if (q == 0) a_out[(size_t)n * COUT + c] = ao;
}

// ---------------------------------------------------------------------------
// 4a) class caps M-step: one 256-thread block per (image b, capsule c).
// ---------------------------------------------------------------------------
__global__ __launch_bounds__(256) void cls_m_kernel(
    const float* __restrict__ pose5, const float* __restrict__ a5,
    const float* __restrict__ X, const float* __restrict__ W,
    const float* __restrict__ bu_p, const float* __restrict__ ba_p,
    float* __restrict__ mu_g, float* __restrict__ inv2_g,
    float* __restrict__ base_g, float* __restrict__ out,
    int first, int last) {
  int blk = blockIdx.x;                 // b*10 + c
  int c = blk % 10, b = blk / 10;
  int t = threadIdx.x;
  int lane = t & 63, wv = t >> 6;
  const float* pg = pose5 + (size_t)b * 16384;
  __shared__ float w_s[16][16];         // [jj][d]
  {
    int d = t & 15, jj = t >> 4;
    w_s[jj][d] = W[(d * 10 + c) * 16 + jj];
  }
  __syncthreads();
  const int d = t & 15;
  float wf[16];
#pragma unroll
  for (int jj = 0; jj < 16; ++jj) wf[jj] = w_s[jj][d];

  float sA = 0.f, sV[16], sV2[16];
#pragma unroll
  for (int p = 0; p < 16; ++p) { sV[p] = 0.f; sV2[p] = 0.f; }
#pragma unroll
  for (int rep = 0; rep < 4; ++rep) {
    int bi = rep * 256 + t;
    int pos = bi >> 4;
    float rw = first ? 0.1f * a5[(size_t)b * 1024 + bi]
                     : X[(size_t)blk * 1024 + bi];
    float ci = (float)(pos >> 3) * 0.125f;
    float cj = (float)(pos & 7) * 0.125f;
    const float* pp = pg + pos * 256 + d * 16;
    float pmr[16];
#pragma unroll
    for (int q = 0; q < 16; ++q) pmr[q] = pp[q];
    sA += rw;
#pragma unroll
    for (int p = 0; p < 16; ++p) {
      int ip = p >> 2, l = p & 3;
      float v = pmr[ip * 4 + 0] * wf[0 * 4 + l] + pmr[ip * 4 + 1] * wf[1 * 4 + l]
              + pmr[ip * 4 + 2] * wf[2 * 4 + l] + pmr[ip * 4 + 3] * wf[3 * 4 + l];
      if (p == 0) v += ci;
      else if (p == 1) v += cj;
      float rv = rw * v;
      sV[p] += rv;
      sV2[p] += rv * v;
    }
  }
#pragma unroll
  for (int off = 1; off < 64; off <<= 1) {
    sA += __shfl_xor(sA, off, 64);
#pragma unroll
    for (int p = 0; p < 16; ++p) {
      sV[p]  += __shfl_xor(sV[p],  off, 64);
      sV2[p] += __shfl_xor(sV2[p], off, 64);
    }
  }
  __shared__ float red[4][36];
  if (lane == 0) {
    red[wv][0] = sA;
#pragma unroll
    for (int p = 0; p < 16; ++p) { red[wv][1 + p] = sV[p]; red[wv][17 + p] = sV2[p]; }
  }
  __syncthreads();
  if (t < 16) {
    int p = t;
    float sAf  = red[0][0] + red[1][0] + red[2][0] + red[3][0];
    float sVf  = red[0][1+p] + red[1][1+p] + red[2][1+p] + red[3][1+p];
    float sV2f = red[0][17+p] + red[1][17+p] + red[2][17+p] + red[3][17+p];
    float inv = 1.f / (sAf + EPS);
    float S = sAf * inv;
    float mu = sVf * inv;
    float sg = sV2f * inv - mu * mu * (2.f - S) + EPS;
    sg = fmaxf(sg, EPS);
    mu_g[blk * 16 + p] = mu;
    inv2_g[blk * 16 + p] = 0.5f / sg;
    float hl = 0.5f * __logf(sg);
    float lsum = hl;
    lsum += __shfl_xor(lsum, 1, 64);
    lsum += __shfl_xor(lsum, 2, 64);
    lsum += __shfl_xor(lsum, 4, 64);
    lsum += __shfl_xor(lsum, 8, 64);
    if (p == 0) {
      float cost = sAf * (16.f * bu_p[c] + lsum);
      float ao = sigmoidf(LAMBDA * (ba_p[c] - cost));
      base_g[blk] = __logf(EPS + ao) - lsum - 16.f * LN2PI_HALF;
      if (last) out[blk] = ao;
    }
  }
}

// ---------------------------------------------------------------------------
// 4b) class caps E-step: 2 blocks of 512 per image; thread = one b_in.
// ---------------------------------------------------------------------------
__global__ __launch_bounds__(512) void cls_e_kernel(
    const float* __restrict__ pose5, const float* __restrict__ a5,
    const float* __restrict__ W,
    const float* __restrict__ mu_g, const float* __restrict__ inv2_g,
    const float* __restrict__ base_g, float* __restrict__ X) {
  int b = blockIdx.x >> 1;
  int t = threadIdx.x;
  int bi = ((blockIdx.x & 1) << 9) + t;
  const float* pg = pose5 + (size_t)b * 16384;
  __shared__ float w2[10][16][16];      // [c][jj][d]
  __shared__ float mu_s[160];
  __shared__ float inv2_s[160];
  __shared__ float base_s[10];
  for (int q = t; q < 2560; q += 512) {
    int dd = q & 15, jj = (q >> 4) & 15, c = q >> 8;
    w2[c][jj][dd] = W[(dd * 10 + c) * 16 + jj];
  }
  if (t < 160) { mu_s[t] = mu_g[b * 160 + t]; inv2_s[t] = inv2_g[b * 160 + t]; }
  if (t >= 160 && t < 170) base_s[t - 160] = base_g[b * 10 + (t - 160)];
  __syncthreads();

  int pos = bi >> 4, d2 = bi & 15;
  float ci = (float)(pos >> 3) * 0.125f;
  float cj = (float)(pos & 7) * 0.125f;
  const float* pp = pg + pos * 256 + d2 * 16;
  float pmr[16];
#pragma unroll
  for (int q = 0; q < 16; ++q) pmr[q] = pp[q];
  float lnap[10];
#pragma unroll
  for (int c = 0; c < 10; ++c) {
    float wf[16];
#pragma unroll
    for (int jj = 0; jj < 16; ++jj) wf[jj] = w2[c][jj][d2];
    float s = base_s[c];
#pragma unroll
    for (int p = 0; p < 16; ++p) {
      int ip = p >> 2, l = p & 3;
      float v = pmr[ip * 4 + 0] * wf[0 * 4 + l] + pmr[ip * 4 + 1] * wf[1 * 4 + l]
              + pmr[ip * 4 + 2] * wf[2 * 4 + l] + pmr[ip * 4 + 3] * wf[3 * 4 + l];
      if (p == 0) v += ci;
      else if (p == 1) v += cj;
      float dd = v - mu_s[c * 16 + p];
      s -= dd * dd * inv2_s[c * 16 + p];
    }
    lnap[c] = s;
  }
  float m = -1e30f;
#pragma unroll
  for (int c = 0; c < 10; ++c) m = fmaxf(m, lnap[c]);
  float Z = 0.f;
  float ex[10];
#pragma unroll
  for (int c = 0; c < 10; ++c) { ex[c] = __expf(lnap[c] - m); Z += ex[c]; }
  float invZ = a5[(size_t)b * 1024 + bi] / Z;
#pragma unroll
  for (int c = 0; c < 10; ++c) X[((size_t)(b * 10 + c)) * 1024 + bi] = ex[c] * invZ;
}

// ---------------------------------------------------------------------------
extern "C" void kernel_launch(void* const* d_in, const int* in_sizes, int n_in,
                              void* d_out, int out_size, void* d_ws, size_t ws_size,
                              hipStream_t stream) {
  const float* x       = (const float*)d_in[0];
  const float* conv1_w = (const float*)d_in[1];
  const float* conv1_b = (const float*)d_in[2];
  const float* pp_w    = (const float*)d_in[3];
  const float* pp_b    = (const float*)d_in[4];
  const float* pa_w    = (const float*)d_in[5];
  const float* pa_b    = (const float*)d_in[6];
  const float* dw1_w   = (const float*)d_in[7];
  const float* dw1_bu  = (const float*)d_in[8];
  const float* dw1_ba  = (const float*)d_in[9];
  const float* cc1_w   = (const float*)d_in[10];
  const float* cc1_bu  = (const float*)d_in[11];
  const float* cc1_ba  = (const float*)d_in[12];
  const float* dw2_w   = (const float*)d_in[13];
  const float* dw2_bu  = (const float*)d_in[14];
  const float* dw2_ba  = (const float*)d_in[15];
  const float* cc2_w   = (const float*)d_in[16];
  const float* cc2_bu  = (const float*)d_in[17];
  const float* cc2_ba  = (const float*)d_in[18];
  const float* cls_w   = (const float*)d_in[19];
  const float* cls_bu  = (const float*)d_in[20];
  const float* cls_ba  = (const float*)d_in[21];
  float* out = (float*)d_out;

  float* ws = (float*)d_ws;
  float* pose1 = ws;                  // 32*30*30*128
  float* a1    = ws + 3686400;        // 32*30*30*8
  float* pose2 = ws + 3916800;        // 32*15*15*128
  float* a2    = ws + 4838400;        // 32*15*15*8
  float* pose3 = ws;                  // 32*15*15*256 (aliases dead pose1)
  float* a3    = ws + 1843200;        // 32*15*15*16
  float* pose4 = ws + 1958400;        // 32*8*8*256
  float* a4    = ws + 2482688;        // 32*8*8*16
  float* pose5 = ws + 2515456;        // 32*8*8*256
  float* a5    = ws + 3039744;        // 32*8*8*16
  float* Xbuf  = ws + 3072512;        // 32*10*1024
  float* mu_g  = ws + 3400192;        // 32*160
  float* inv2_g= ws + 3405312;        // 32*160
  float* base_g= ws + 3410432;        // 32*10

  stem_primary_kernel<<<2880, 256, 0, stream>>>(x, conv1_w, conv1_b,
                                                pp_w, pp_b, pa_w, pa_b, pose1, a1);
  dw_caps_kernel<7, 8, 30, 30, 15, 15, 5, 3><<<768, 256, 0, stream>>>(
      pose1, a1, dw1_w, dw1_bu, dw1_ba, pose2, a2);
  // cc1: 7200 problems, 4 per block (wave each)
  cc_em_kernel<8><<<1800, 256, 0, stream>>>(pose2, a2, cc1_w, cc1_bu, cc1_ba, pose3, a3);
  dw_caps_kernel<5, 16, 15, 15, 8, 8, 8, 1><<<512, 256, 0, stream>>>(
      pose3, a3, dw2_w, dw2_bu, dw2_ba, pose4, a4);
  // cc2: 2048 problems, 4 per block
  cc_em_kernel<16><<<512, 256, 0, stream>>>(pose4, a4, cc2_w, cc2_bu, cc2_ba, pose5, a5);
  cls_m_kernel<<<320, 256, 0, stream>>>(pose5, a5, Xbuf, cls_w, cls_bu, cls_ba,
                                        mu_g, inv2_g, base_g, out, 1, 0);
  cls_e_kernel<<<64, 512, 0, stream>>>(pose5, a5, cls_w, mu_g, inv2_g, base_g, Xbuf);
  cls_m_kernel<<<320, 256, 0, stream>>>(pose5, a5, Xbuf, cls_w, cls_bu, cls_ba,
                                        mu_g, inv2_g, base_g, out, 0, 0);
  cls_e_kernel<<<64, 512, 0, stream>>>(pose5, a5, cls_w, mu_g, inv2_g, base_g, Xbuf);
  cls_m_kernel<<<320, 256, 0, stream>>>(pose5, a5, Xbuf, cls_w, cls_bu, cls_ba,
                                        mu_g, inv2_g, base_g, out, 0, 1);
}